// Round 17
// baseline (1069.588 us; speedup 1.0000x reference)
//
#include <hip/hip_runtime.h>
#include <cstdint>

#define D_  2048
#define H_  16
#define HD_ 128
#define FF_ 8192
#define T_  2048
#define B_  2
#define BT_ (B_*T_)
#define NP_ (B_*H_)        // 32 (b,h) pairs
#define QKVLD_ (3*D_)      // fused qkv row stride (6144)

typedef __attribute__((ext_vector_type(8))) _Float16 half8;
typedef __attribute__((ext_vector_type(4))) float   floatx4;

// async global->LDS, 16B per lane; LDS dest = wave-uniform base + lane*16
__device__ __forceinline__ void gl_lds16(const void* g, void* l) {
  __builtin_amdgcn_global_load_lds(
      (const __attribute__((address_space(1))) void*)(uintptr_t)g,
      (__attribute__((address_space(3))) void*)(uintptr_t)l,
      16, 0, 0);
}

// ---------------- weight convert + transpose: W[K][N] f32 -> Wt[N][K] f16 ----
// v2: 128k x 32n tiles; float4 global loads (128B/8-lane cluster) and uint2
// packed stores giving 256B-contiguous output rows (2x the old write width).
// LDS pad 33 (column read is ~4-way conflicted; HBM-bound anyway).
__global__ void wconv_kernel(const float* __restrict__ W, _Float16* __restrict__ Wt,
                             int K, int N) {
  __shared__ float tile[128][33];
  int n0 = blockIdx.x * 32, k0 = blockIdx.y * 128;
  int tid = threadIdx.x;            // 256
  int lr = tid >> 3;                // 0..31 (row within pass)
  int lc = (tid & 7) * 4;           // 0..28 (f32 col)
#pragma unroll
  for (int p = 0; p < 4; ++p) {
    int r = p * 32 + lr;
    float4 v = *(const float4*)(W + (size_t)(k0 + r) * N + n0 + lc);
    tile[r][lc] = v.x; tile[r][lc + 1] = v.y;
    tile[r][lc + 2] = v.z; tile[r][lc + 3] = v.w;
  }
  __syncthreads();
  int nr = tid >> 5;                // 0..7 (n-row within pass)
  int kc = (tid & 31) * 4;          // 0..124 (k col, step 4)
#pragma unroll
  for (int p = 0; p < 4; ++p) {
    int n = p * 8 + nr;
    _Float16 h4[4] __attribute__((aligned(8)));
    h4[0] = (_Float16)tile[kc][n];
    h4[1] = (_Float16)tile[kc + 1][n];
    h4[2] = (_Float16)tile[kc + 2][n];
    h4[3] = (_Float16)tile[kc + 3][n];
    *(uint2*)(Wt + (size_t)(n0 + n) * K + k0 + kc) = *(const uint2*)h4;
  }
}

// ---------------- rmsnorm: fp32 row -> fp16 row --------------------------------
__global__ void rmsnorm_kernel(const float* __restrict__ x, const float* __restrict__ g,
                               _Float16* __restrict__ out) {
  int row = blockIdx.x, tid = threadIdx.x;
  const float4* xr = (const float4*)(x + (size_t)row * D_);
  float4 v1 = xr[tid], v2 = xr[tid + 256];
  float ss = v1.x*v1.x + v1.y*v1.y + v1.z*v1.z + v1.w*v1.w
           + v2.x*v2.x + v2.y*v2.y + v2.z*v2.z + v2.w*v2.w;
  __shared__ float red[256];
  red[tid] = ss; __syncthreads();
  for (int s = 128; s > 0; s >>= 1) { if (tid < s) red[tid] += red[tid + s]; __syncthreads(); }
  float rs = rsqrtf(red[0] * (1.0f / D_) + 1e-6f);
  float4 ga = ((const float4*)g)[tid], gb = ((const float4*)g)[tid + 256];
  _Float16* orow = out + (size_t)row * D_;
  _Float16 t[4] __attribute__((aligned(8)));
  t[0] = (_Float16)(v1.x * rs * ga.x);
  t[1] = (_Float16)(v1.y * rs * ga.y);
  t[2] = (_Float16)(v1.z * rs * ga.z);
  t[3] = (_Float16)(v1.w * rs * ga.w);
  *(uint2*)(orow + tid * 4) = *(const uint2*)t;
  t[0] = (_Float16)(v2.x * rs * gb.x);
  t[1] = (_Float16)(v2.y * rs * gb.y);
  t[2] = (_Float16)(v2.z * rs * gb.z);
  t[3] = (_Float16)(v2.w * rs * gb.w);
  *(uint2*)(orow + (tid + 256) * 4) = *(const uint2*)t;
}

// ---------------- fused split-K reduce + rmsnorm (Wo path) ----------------------
// x1 = p0 + p1 + res; hb = rmsnorm(x1, g)   (one block per row)
__global__ void addredrms_kernel(const float* __restrict__ parts,
                                 const float* __restrict__ res,
                                 const float* __restrict__ g,
                                 float* __restrict__ x1, _Float16* __restrict__ hb) {
  int row = blockIdx.x, tid = threadIdx.x;
  const size_t MN = (size_t)BT_ * D_;
  size_t base = (size_t)row * D_;
  float4 a1 = *(const float4*)(parts + base + tid * 4);
  float4 b1 = *(const float4*)(parts + MN + base + tid * 4);
  float4 r1 = *(const float4*)(res + base + tid * 4);
  float4 a2 = *(const float4*)(parts + base + (tid + 256) * 4);
  float4 b2 = *(const float4*)(parts + MN + base + (tid + 256) * 4);
  float4 r2 = *(const float4*)(res + base + (tid + 256) * 4);
  float4 v1, v2;
  v1.x = a1.x + b1.x + r1.x; v1.y = a1.y + b1.y + r1.y;
  v1.z = a1.z + b1.z + r1.z; v1.w = a1.w + b1.w + r1.w;
  v2.x = a2.x + b2.x + r2.x; v2.y = a2.y + b2.y + r2.y;
  v2.z = a2.z + b2.z + r2.z; v2.w = a2.w + b2.w + r2.w;
  *(float4*)(x1 + base + tid * 4) = v1;
  *(float4*)(x1 + base + (tid + 256) * 4) = v2;
  float ss = v1.x*v1.x + v1.y*v1.y + v1.z*v1.z + v1.w*v1.w
           + v2.x*v2.x + v2.y*v2.y + v2.z*v2.z + v2.w*v2.w;
  __shared__ float red[256];
  red[tid] = ss; __syncthreads();
  for (int s = 128; s > 0; s >>= 1) { if (tid < s) red[tid] += red[tid + s]; __syncthreads(); }
  float rs = rsqrtf(red[0] * (1.0f / D_) + 1e-6f);
  float4 ga = ((const float4*)g)[tid], gb = ((const float4*)g)[tid + 256];
  _Float16* orow = hb + base;
  _Float16 t[4] __attribute__((aligned(8)));
  t[0] = (_Float16)(v1.x * rs * ga.x);
  t[1] = (_Float16)(v1.y * rs * ga.y);
  t[2] = (_Float16)(v1.z * rs * ga.z);
  t[3] = (_Float16)(v1.w * rs * ga.w);
  *(uint2*)(orow + tid * 4) = *(const uint2*)t;
  t[0] = (_Float16)(v2.x * rs * gb.x);
  t[1] = (_Float16)(v2.y * rs * gb.y);
  t[2] = (_Float16)(v2.z * rs * gb.z);
  t[3] = (_Float16)(v2.w * rs * gb.w);
  *(uint2*)(orow + (tid + 256) * 4) = *(const uint2*)t;
}

// ================================================================================
// 8-phase GEMM (m201 schedule), C = A @ Bt^T. 256x256 tile, BK=64, 8 waves
// (2Mx4N), wave tile 128x64. LDS: [slot0: A 32K | B 32K][slot1] = 128 KiB dbuf.
// K-loop unrolled 2 tiles/iter (literal slots); ds_reads via 8 precomputed
// per-lane base VGPRs + literal imms; stage addrs = 2 advancing pointers.
// vmcnt(4) once per K-tile; never 0 mid-loop. R13/R15-measured config.
// OUTMODE: 0 -> C f16 = acc; 1 -> C f32 = acc + Res; 2 -> C f32 partial at bz;
//          3 -> C f16 = silu(gate[o]) * acc  (gate = (const _Float16*)Res,
//               fused SwiGLU epilogue; may write over gate in place).
template<int OUTMODE>
__global__ __launch_bounds__(512, 2) void gemm256(
    const _Float16* __restrict__ A, const _Float16* __restrict__ Bt,
    void* __restrict__ Cv, const float* __restrict__ Res,
    int M, int N, int K, int lda, int ldb, int ldc)
{
  extern __shared__ _Float16 smem[];   // [2][A:16384 | B:16384] elems

  // XCD-bijective remap
  const int gx = gridDim.x, gy = gridDim.y, gz = gridDim.z;
  int pid = (blockIdx.z * gy + blockIdx.y) * gx + blockIdx.x;
  const int qch = (gx * gy * gz) >> 3;
  int lid = (pid & 7) * qch + (pid >> 3);
  const int bx = lid % gx; lid /= gx;
  const int by = lid % gy; const int bz = lid / gy;

  const int tid  = threadIdx.x;
  const int lane = tid & 63;
  const int w    = tid >> 6;          // 0..7
  const int wm   = w >> 2;            // 0..1
  const int wn   = w & 3;             // 0..3
  const int l15  = lane & 15, q4 = lane >> 4;
  const int m0   = by * 256;
  const int n0   = bx * 256;
  const int KP   = K / gz;
  const int koff = bz * KP;
  const int NT   = KP >> 6;           // K-tiles of 64 (even)

  const int srow8  = lane >> 3;
  const int schunk = (((lane & 7) ^ (srow8 & 7)) << 3);
  const _Float16* AgP = A  + (size_t)(m0 + w * 8 + srow8) * lda + schunk + koff;
  const _Float16* BgP = Bt + (size_t)(n0 + w * 8 + srow8) * ldb + schunk + koff;
  const int ldsW = w * 512;

  const int c0 = ((q4 ^ (l15 & 7)) << 3);
  const int c1 = c0 ^ 32;
  const int arow_e = (wm * 128 + l15) * 64;
  const int brow_e = (wn * 64 + l15) * 64;
  const _Float16* aB[2][2];   // [slot][kk] — literal-indexed only
  const _Float16* bB[2][2];
  aB[0][0] = smem + arow_e + c0;          aB[0][1] = smem + arow_e + c1;
  aB[1][0] = aB[0][0] + 32768;            aB[1][1] = aB[0][1] + 32768;
  bB[0][0] = smem + 16384 + brow_e + c0;  bB[0][1] = smem + 16384 + brow_e + c1;
  bB[1][0] = bB[0][0] + 32768;            bB[1][1] = bB[0][1] + 32768;

  floatx4 acc[8][4];
#pragma unroll
  for (int i = 0; i < 8; ++i)
#pragma unroll
    for (int j = 0; j < 4; ++j)
#pragma unroll
      for (int r = 0; r < 4; ++r) acc[i][j][r] = 0.0f;

  half8 bf[2][4];
  half8 af0[4], af1[4];

#define STA(S, h, s, KO)                                                     \
  gl_lds16(AgP + (size_t)((h) * 128 + (s) * 64) * lda + (KO),                \
           smem + (S) * 32768 + (h) * 8192 + (s) * 4096 + ldsW)
#define STB(S, h, s, KO)                                                     \
  gl_lds16(BgP + (size_t)((h) * 128 + (s) * 64) * ldb + (KO),                \
           smem + (S) * 32768 + 16384 + (h) * 8192 + (s) * 4096 + ldsW)

#define SB0   __builtin_amdgcn_sched_barrier(0)
#define BARR  __builtin_amdgcn_s_barrier()
#define LGKM0 asm volatile("s_waitcnt lgkmcnt(0)" ::: "memory")

#define RD_B8(S)                                                             \
  { _Pragma("unroll")                                                        \
    for (int j = 0; j < 4; ++j) {                                            \
      bf[0][j] = *(const half8*)(bB[S][0] + j * 1024);                       \
      bf[1][j] = *(const half8*)(bB[S][1] + j * 1024);                       \
    } }
#define RD_A4(S, q, af)                                                      \
  { _Pragma("unroll")                                                        \
    for (int i2 = 0; i2 < 2; ++i2) {                                         \
      af[i2*2+0] = *(const half8*)(aB[S][0] + ((q)*2+i2) * 1024);            \
      af[i2*2+1] = *(const half8*)(aB[S][1] + ((q)*2+i2) * 1024);            \
    } }
#define MFMA_Q(q, af)                                                        \
  { _Pragma("unroll")                                                        \
    for (int kk = 0; kk < 2; ++kk)                                           \
      _Pragma("unroll")                                                      \
      for (int i2 = 0; i2 < 2; ++i2)                                         \
        _Pragma("unroll")                                                    \
        for (int j = 0; j < 4; ++j)                                          \
          acc[(q)*2+i2][j] = __builtin_amdgcn_mfma_f32_16x16x32_f16(         \
              af[i2*2+kk], bf[kk][j], acc[(q)*2+i2][j], 0, 0, 0);            \
  }

#define TILE(S, t, KOA, KOB)                                                 \
  {                                                                          \
    const bool s1 = (t) + 1 < NT, s2 = (t) + 2 < NT;                         \
    /* Ph1: all B + A-quad0 */                                               \
    RD_B8(S); RD_A4(S, 0, af0);                                              \
    if (s1) { STA((S) ^ 1, 0, 0, KOA); STA((S) ^ 1, 0, 1, KOA); }            \
    asm volatile("s_waitcnt lgkmcnt(8)" ::: "memory");                       \
    SB0; BARR; LGKM0; SB0;                                                   \
    __builtin_amdgcn_s_setprio(1); MFMA_Q(0, af0); __builtin_amdgcn_s_setprio(0); \
    SB0; BARR;                                                               \
    /* Ph2: A-quad1 */                                                       \
    RD_A4(S, 1, af1);                                                        \
    if (s1) { STA((S) ^ 1, 1, 0, KOA); STA((S) ^ 1, 1, 1, KOA); }            \
    SB0; BARR; LGKM0; SB0;                                                   \
    __builtin_amdgcn_s_setprio(1); MFMA_Q(1, af1); __builtin_amdgcn_s_setprio(0); \
    SB0; BARR;                                                               \
    /* Ph3: A-quad2 */                                                       \
    RD_A4(S, 2, af0);                                                        \
    if (s2) { STB(S, 0, 0, KOB); STB(S, 0, 1, KOB); }                        \
    SB0; BARR; LGKM0; SB0;                                                   \
    __builtin_amdgcn_s_setprio(1); MFMA_Q(2, af0); __builtin_amdgcn_s_setprio(0); \
    SB0; BARR;                                                               \
    /* Ph4: A-quad3 */                                                       \
    RD_A4(S, 3, af1);                                                        \
    if (s2) { STB(S, 1, 0, KOB); STB(S, 1, 1, KOB); }                        \
    SB0; BARR; LGKM0; SB0;                                                   \
    __builtin_amdgcn_s_setprio(1); MFMA_Q(3, af1); __builtin_amdgcn_s_setprio(0); \
    SB0;                                                                     \
    if (s2)      asm volatile("s_waitcnt vmcnt(4)" ::: "memory");            \
    else if (s1) asm volatile("s_waitcnt vmcnt(0)" ::: "memory");            \
    BARR;                                                                    \
  }

  STA(0, 0, 0, 0); STA(0, 0, 1, 0); STA(0, 1, 0, 0); STA(0, 1, 1, 0);
  STB(0, 0, 0, 0); STB(0, 0, 1, 0); STB(0, 1, 0, 0); STB(0, 1, 1, 0);
  if (NT > 1) {
    STB(1, 0, 0, 64); STB(1, 0, 1, 64); STB(1, 1, 0, 64); STB(1, 1, 1, 64);
    asm volatile("s_waitcnt vmcnt(4)" ::: "memory");
  } else {
    asm volatile("s_waitcnt vmcnt(0)" ::: "memory");
  }
  BARR;

  for (int t = 0; t < NT; t += 2) {
    TILE(0, t,     64, 128);
    TILE(1, t + 1, 128, 192);
    AgP += 128; BgP += 128;
  }

#undef STA
#undef STB
#undef SB0
#undef BARR
#undef LGKM0
#undef RD_B8
#undef RD_A4
#undef MFMA_Q
#undef TILE

  const int crow0 = m0 + wm * 128 + q4 * 4;
  const int ccol0 = n0 + wn * 64 + l15;
#pragma unroll
  for (int i = 0; i < 8; ++i)
#pragma unroll
    for (int j = 0; j < 4; ++j)
#pragma unroll
      for (int r = 0; r < 4; ++r) {
        size_t o = (size_t)(crow0 + i * 16 + r) * ldc + (ccol0 + j * 16);
        if constexpr (OUTMODE == 0)      ((_Float16*)Cv)[o] = (_Float16)acc[i][j][r];
        else if constexpr (OUTMODE == 1) ((float*)Cv)[o] = acc[i][j][r] + Res[o];
        else if constexpr (OUTMODE == 3) {
          float gv = (float)((const _Float16*)Res)[o];
          float si = gv / (1.0f + __expf(-gv));
          ((_Float16*)Cv)[o] = (_Float16)(si * acc[i][j][r]);
        }
        else ((float*)Cv)[(size_t)bz * M * ldc + o] = acc[i][j][r];
      }
}

// ---------------- split-K reduce: out = p0 + p1 + res (all f32) -----------------
__global__ void addred_kernel(const float* __restrict__ parts, const float* __restrict__ res,
                              float* __restrict__ out) {
  size_t i = ((size_t)blockIdx.x * 256 + threadIdx.x) * 4;
  const size_t MN = (size_t)BT_ * D_;
  float4 a = *(const float4*)(parts + i);
  float4 b = *(const float4*)(parts + MN + i);
  float4 r = *(const float4*)(res + i);
  float4 o;
  o.x = a.x + b.x + r.x; o.y = a.y + b.y + r.y;
  o.z = a.z + b.z + r.z; o.w = a.w + b.w + r.w;
  *(float4*)(out + i) = o;
}

// ================================================================================
// K pack: post-rope K -> fragment-contiguous kp[pair][t/16][d/32][lane][8].
__global__ void kpack_kernel(const _Float16* __restrict__ qkv, _Float16* __restrict__ kp) {
  __shared__ _Float16 tile[32][40];    // [t][d], padded
  int t0 = blockIdx.x * 32, d0 = blockIdx.y * 32, bh = blockIdx.z;
  int b = bh >> 4, h = bh & 15;
  int tx = threadIdx.x, ty = threadIdx.y;   // 32 x 8
  const _Float16* kb = qkv + (size_t)b * T_ * QKVLD_ + D_ + (size_t)h * HD_;
#pragma unroll
  for (int r = 0; r < 32; r += 8)
    tile[ty + r][tx] = kb[(size_t)(t0 + ty + r) * QKVLD_ + d0 + tx];
  __syncthreads();
  int tid = ty * 32 + tx;
  if (tid < 128) {
    int tt = tid & 31;            // t within tile
    int c  = tid >> 5;            // d chunk of 8 (0..3)
    int t = t0 + tt, d = d0 + c * 8;
    _Float16 v8[8] __attribute__((aligned(16)));
#pragma unroll
    for (int e = 0; e < 8; ++e) v8[e] = tile[tt][c * 8 + e];
    size_t frag = ((size_t)bh * (T_ / 16) + (t >> 4)) * 4 + (d >> 5);
    int lane = (t & 15) + (((d >> 3) & 3) << 4);
    *(uint4*)(kp + frag * 512 + lane * 8) = *(const uint4*)v8;
  }
}

// ---------------- V pack: qkv V -> V^T fragments vp[pair][t/128][ks][jd][lane][8]
__global__ void vpack_kernel(const _Float16* __restrict__ qkv, _Float16* __restrict__ vp) {
  __shared__ _Float16 tile[32][40];    // [t][d], padded
  int t0 = blockIdx.x * 32, d0 = blockIdx.y * 32, bh = blockIdx.z;
  int b = bh >> 4, h = bh & 15;
  int tx = threadIdx.x, ty = threadIdx.y;   // 32 x 8
  const _Float16* vb = qkv + (size_t)b * T_ * QKVLD_ + 2 * D_ + (size_t)h * HD_;
#pragma unroll
  for (int r = 0; r < 32; r += 8)
    tile[ty + r][tx] = vb[(size_t)(t0 + ty + r) * QKVLD_ + d0 + tx];
  __syncthreads();
  int tid = ty * 32 + tx;
  if (tid < 128) {
    int dd = tid & 31;            // d within tile
    int tg = tid >> 5;            // t chunk of 8 (0..3)
    int d = d0 + dd, t = t0 + tg * 8;
    _Float16 v8[8] __attribute__((aligned(16)));
#pragma unroll
    for (int e = 0; e < 8; ++e) v8[e] = tile[tg * 8 + e][dd];
    size_t frag = (((size_t)bh * 16 + (t >> 7)) * 4 + ((t >> 5) & 3)) * 8 + (d >> 4);
    int lane = (d & 15) + (((t >> 3) & 3) << 4);
    *(uint4*)(vp + frag * 512 + lane * 8) = *(const uint4*)v8;
  }
}

// ================================================================================
// Fused flash attention (causal). R15/R16-measured config: one 128-row q-block
// per WG, 4 waves, grid (32 pairs, 16) = 512 WGs, (256,2) -> ~128 VGPR.
// K/V from PACKED fragment layouts (base + lane*16, fully coalesced). 8-wide
// double-buffered K/V batches; V batch0 issued before softmax. setprio(1)
// around both MFMA clusters (T5). NEW: exact defer-rescale — when a tile's
// pm <= running max, sc==1 exactly, so skip m/l/Oa rescale (T13-exact).
// Online softmax f32 via shfl_xor; P via wave-private LDS rows (no barriers).
__global__ __launch_bounds__(256, 2) void fattn_kernel(
    const _Float16* __restrict__ qkv, const _Float16* __restrict__ kp,
    const _Float16* __restrict__ vp, _Float16* __restrict__ ob)
{
  __shared__ _Float16 Pl[128 * 136];   // row stride 136 f16 (pad vs bank conflicts)
  const int pr = blockIdx.x;           // pair 0..31
  const int yq = blockIdx.y;           // 0..15
  const int qb = (yq < 8) ? yq : 23 - yq;   // CU-pair work balance
  const int b = pr >> 4, h = pr & 15;
  const int lane = threadIdx.x & 63, w = threadIdx.x >> 6;
  const int l15 = lane & 15, q4 = lane >> 4;
  const float scale = 0.08838834764831845f;   // 1/sqrt(128)

  const _Float16* qg = qkv + (size_t)b * T_ * QKVLD_ + (size_t)h * HD_;
  _Float16* og = ob + (size_t)b * T_ * D_ + (size_t)h * HD_;
  const _Float16* kpp = kp + (size_t)pr * 128 * 4 * 512 + lane * 8;
  const _Float16* vpp = vp + (size_t)pr * 16 * 32 * 512 + lane * 8;

  const int qrow0 = qb * 128 + w * 32;

  // Q fragments: lane holds Q[row=l15(+16i)][k=kf*32+q4*8 .. +8]
  half8 qf[2][4];
#pragma unroll
  for (int i = 0; i < 2; ++i)
#pragma unroll
    for (int kf = 0; kf < 4; ++kf)
      qf[i][kf] = *(const half8*)(qg + (size_t)(qrow0 + i * 16 + l15) * QKVLD_
                                     + kf * 32 + q4 * 8);

  floatx4 Oa[2][8];
  float m[8], l[8];
#pragma unroll
  for (int i = 0; i < 2; ++i)
#pragma unroll
    for (int j = 0; j < 8; ++j)
#pragma unroll
      for (int r = 0; r < 4; ++r) Oa[i][j][r] = 0.f;
#pragma unroll
  for (int z = 0; z < 8; ++z) { m[z] = -1e30f; l[z] = 0.f; }

  for (int kt = 0; kt <= qb; ++kt) {
    // K fragment (j, kf) at kT + (j*4 + kf)*512
    const _Float16* kT = kpp + (size_t)kt * 8 * 4 * 512;
    half8 k0[8], k1[8];
#pragma unroll
    for (int j = 0; j < 8; ++j)
      k0[j] = *(const half8*)(kT + j * 2048);
    floatx4 s[2][8];
#pragma unroll
    for (int i = 0; i < 2; ++i)
#pragma unroll
      for (int j = 0; j < 8; ++j)
#pragma unroll
        for (int r = 0; r < 4; ++r) s[i][j][r] = 0.f;
#pragma unroll
    for (int kf = 0; kf < 4; ++kf) {
      if (kf < 3) {
#pragma unroll
        for (int j = 0; j < 8; ++j) {
          half8 nx = *(const half8*)(kT + j * 2048 + (kf + 1) * 512);
          if (kf & 1) k0[j] = nx; else k1[j] = nx;
        }
      }
      __builtin_amdgcn_s_setprio(1);
#pragma unroll
      for (int j = 0; j < 8; ++j) {
        half8 cur = (kf & 1) ? k1[j] : k0[j];
        s[0][j] = __builtin_amdgcn_mfma_f32_16x16x32_f16(qf[0][kf], cur, s[0][j], 0, 0, 0);
        s[1][j] = __builtin_amdgcn_mfma_f32_16x16x32_f16(qf[1][kf], cur, s[1][j], 0, 0, 0);
      }
      __builtin_amdgcn_s_setprio(0);
    }
    // scale (f32, matches reference order)
#pragma unroll
    for (int i = 0; i < 2; ++i)
#pragma unroll
      for (int j = 0; j < 8; ++j)
#pragma unroll
        for (int r = 0; r < 4; ++r) s[i][j][r] *= scale;
    // causal mask (diagonal tile only)
    if (kt == qb) {
#pragma unroll
      for (int i = 0; i < 2; ++i)
#pragma unroll
        for (int j = 0; j < 8; ++j)
#pragma unroll
          for (int r = 0; r < 4; ++r)
            if (j * 16 + l15 > w * 32 + i * 16 + q4 * 4 + r) s[i][j][r] = -1e30f;
    }
    // ---- V ks=0 batch (fragment (ks, jd) at vT + (ks*8 + jd)*512) ----
    const _Float16* vT = vpp + (size_t)kt * 32 * 512;
    half8 v0[8], v1[8];
#pragma unroll
    for (int jd = 0; jd < 8; ++jd)
      v0[jd] = *(const half8*)(vT + jd * 512);
    // ---- online softmax (per lane: 8 rows = 2i x 4r) ----
#pragma unroll
    for (int i = 0; i < 2; ++i)
#pragma unroll
      for (int r = 0; r < 4; ++r) {
        const int z = i * 4 + r;
        float pm = s[i][0][r];
#pragma unroll
        for (int j = 1; j < 8; ++j) pm = fmaxf(pm, s[i][j][r]);
        pm = fmaxf(pm, __shfl_xor(pm, 1));
        pm = fmaxf(pm, __shfl_xor(pm, 2));
        pm = fmaxf(pm, __shfl_xor(pm, 4));
        pm = fmaxf(pm, __shfl_xor(pm, 8));
        if (pm > m[z]) {          // exact defer: sc==1 when pm <= m[z]
          float sc = __expf(m[z] - pm);
          m[z] = pm;
          l[z] *= sc;
#pragma unroll
          for (int jd = 0; jd < 8; ++jd) Oa[i][jd][r] *= sc;
        }
        float ls = 0.f;
#pragma unroll
        for (int j = 0; j < 8; ++j) {
          float e = __expf(s[i][j][r] - m[z]);
          s[i][j][r] = e;
          ls += e;
        }
        ls += __shfl_xor(ls, 1);
        ls += __shfl_xor(ls, 2);
        ls += __shfl_xor(ls, 4);
        ls += __shfl_xor(ls, 8);
        l[z] += ls;
      }
    // ---- P -> LDS (wave-private rows; no barrier needed) ----
#pragma unroll
    for (int i = 0; i < 2; ++i)
#pragma unroll
      for (int r = 0; r < 4; ++r) {
        _Float16* prow = &Pl[(size_t)(w * 32 + i * 16 + q4 * 4 + r) * 136 + l15];
#pragma unroll
        for (int j = 0; j < 8; ++j) prow[j * 16] = (_Float16)s[i][j][r];
      }
    // ---- O += P @ V, V double-buffered over ks ----
#pragma unroll
    for (int ks = 0; ks < 4; ++ks) {
      if (ks < 3) {
#pragma unroll
        for (int jd = 0; jd < 8; ++jd) {
          half8 nx = *(const half8*)(vT + ((ks + 1) * 8 + jd) * 512);
          if (ks & 1) v0[jd] = nx; else v1[jd] = nx;
        }
      }
      half8 pf0 = *(const half8*)&Pl[(size_t)(w * 32 + l15) * 136 + ks * 32 + q4 * 8];
      half8 pf1 = *(const half8*)&Pl[(size_t)(w * 32 + 16 + l15) * 136 + ks * 32 + q4 * 8];
      __builtin_amdgcn_s_setprio(1);
#pragma unroll
      for (int jd = 0; jd < 8; ++jd) {
        half8 vf = (ks & 1) ? v1[jd] : v0[jd];
        Oa[0][jd] = __builtin_amdgcn_mfma_f32_16x16x32_f16(pf0, vf, Oa[0][jd], 0, 0, 0);
        Oa[1][jd] = __builtin_amdgcn_mfma_f32_16x16x32_f16(pf1, vf, Oa[1][jd], 0, 0, 0);
      }
      __builtin_amdgcn_s_setprio(0);
    }
  }
  // ---- epilogue: O / l -> ob ----
#pragma unroll
  for (int i = 0; i < 2; ++i)
#pragma unroll
    for (int r = 0; r < 4; ++r) {
      float inv = 1.0f / l[i * 4 + r];
      _Float16* orow = og + (size_t)(qrow0 + i * 16 + q4 * 4 + r) * D_;
#pragma unroll
      for (int jd = 0; jd < 8; ++jd)
        orow[jd * 16 + l15] = (_Float16)(Oa[i][jd][r] * inv);
    }
}

// ---------------- RoPE on fused qkv (q at col 0, k at col D_) -------------------
__global__ void rope_kernel(_Float16* __restrict__ qkv, const void* __restrict__ pos) {
  int gid = blockIdx.x * 256 + threadIdx.x;   // BT_*H_*64 threads
  int d = gid & 63;
  int h = (gid >> 6) & 15;
  int bt = gid >> 10;
  const int* pi = (const int*)pos;
  long long pv = (pi[1] == 0 && pi[2] == 1) ? ((const long long*)pos)[bt]
                                            : (long long)pi[bt];
  float inv = exp2f((float)d * -0.2076205059304601f);  // 10000^(-d/64)
  float ang = (float)pv * inv;
  float s, c;
  sincosf(ang, &s, &c);
  size_t base = (size_t)bt * QKVLD_ + (size_t)h * HD_ + d;
  _Float16* q = qkv;
  _Float16* k = qkv + D_;
  float x1v = (float)q[base], x2v = (float)q[base + 64];
  q[base]      = (_Float16)(x1v * c - x2v * s);
  q[base + 64] = (_Float16)(x2v * c + x1v * s);
  x1v = (float)k[base]; x2v = (float)k[base + 64];
  k[base]      = (_Float16)(x1v * c - x2v * s);
  k[base + 64] = (_Float16)(x2v * c + x1v * s);
}

// ================================================================================
extern "C" void kernel_launch(void* const* d_in, const int* in_sizes, int n_in,
                              void* d_out, int out_size, void* d_ws, size_t ws_size,
                              hipStream_t stream) {
  (void)in_sizes; (void)n_in; (void)out_size;
  const float* x   = (const float*)d_in[0];
  const void*  pos = d_in[1];
  const float* W[7] = { (const float*)d_in[2], (const float*)d_in[3],
                        (const float*)d_in[4], (const float*)d_in[5],
                        (const float*)d_in[6], (const float*)d_in[7],
                        (const float*)d_in[8] };              // q k v o g u d
  const float* g1  = (const float*)d_in[9];
  const float* g2  = (const float*)d_in[10];
  float* out = (float*)d_out;

  const int wk[7] = { D_, D_, D_, D_, D_, D_, FF_ };
  const int wn[7] = { D_, D_, D_, D_, FF_, FF_, D_ };

  char* p = (char*)d_ws;
  auto carve = [&](size_t bytes) { char* r = p; p += (bytes + 255) & ~(size_t)255; return r; };

  _Float16* scratch = (_Float16*)carve((size_t)64 * 1024 * 1024);  // Wo parts / gate
  const size_t FLAT_NEED = (size_t)336 * 1024 * 1024;
  bool flat = ws_size >= FLAT_NEED;
  _Float16* w16[7];
  if (flat) {
    // q,k,v carved contiguously -> fused QKV weight matrix [6144][2048]
    for (int i = 0; i < 7; i++) w16[i] = (_Float16*)carve((size_t)wk[i] * wn[i] * 2);
  } else {
    _Float16* wslot = (_Float16*)carve((size_t)D_ * FF_ * 2);      // 32 MB slot
    w16[0] = wslot;
    w16[1] = wslot + (size_t)D_ * D_;
    w16[2] = wslot + (size_t)2 * D_ * D_;
    w16[3] = w16[4] = w16[5] = w16[6] = wslot;
  }
  _Float16* qkv = (_Float16*)carve((size_t)BT_ * QKVLD_ * 2);  // 48 MB
  _Float16* ob  = (_Float16*)carve((size_t)BT_ * D_ * 2);      // 16 MB (contig after qkv)
  _Float16* xn  = (_Float16*)carve((size_t)BT_ * D_ * 2);      // 16 MB; later: kp, hb
  _Float16* vt  = (_Float16*)carve((size_t)BT_ * D_ * 2);      // 16 MB (vp)
  float*    x1  = (float*)   carve((size_t)BT_ * D_ * 4);      // 32 MB
  _Float16* gate = scratch;      // 64 MB region; becomes hu in place (OUTMODE 3)
  _Float16* hb   = xn;
  _Float16* kpb  = xn;           // K packed (16 MB); xn dead after qkv GEMM, reborn as hb later
  _Float16* vpb  = vt;           // V packed (16 MB)
  float* oparts = (float*)scratch; // Wo split-K partials (2 x 32 MB)
  float* dparts = (float*)qkv;     // Wd split-K partials (2 x 32 MB); qkv dead by then

  dim3 b328(32, 8);
  auto conv = [&](int i) {
    wconv_kernel<<<dim3(wn[i] / 32, wk[i] / 128), 256, 0, stream>>>(W[i], w16[i], wk[i], wn[i]);
  };
  if (flat) for (int i = 0; i < 7; i++) conv(i);

  // xn = rmsnorm(x, g1)
  rmsnorm_kernel<<<BT_, 256, 0, stream>>>(x, g1, xn);

  // fused qkv projection: [BT][6144] = xn @ [Wq;Wk;Wv]^T   (384 WGs)
  if (!flat) { conv(0); conv(1); conv(2); }
  gemm256<0><<<dim3(QKVLD_ / 256, BT_ / 256, 1), 512, 131072, stream>>>(
      xn, w16[0], qkv, nullptr, BT_, QKVLD_, D_, D_, D_, QKVLD_);

  // rope(q, k) in fused layout
  rope_kernel<<<(BT_ * H_ * 64) / 256, 256, 0, stream>>>(qkv, pos);

  // pack K (post-rope) and V into MFMA-fragment-contiguous layouts
  kpack_kernel<<<dim3(T_ / 32, HD_ / 32, NP_), b328, 0, stream>>>(qkv, kpb);
  vpack_kernel<<<dim3(T_ / 32, HD_ / 32, NP_), b328, 0, stream>>>(qkv, vpb);

  // fused flash attention: ob = softmax(QK^T/sqrt(d), causal) @ V  (512 WGs)
  fattn_kernel<<<dim3(NP_, 16), 256, 0, stream>>>(qkv, kpb, vpb, ob);

  // x1 = x + o @ Wo : split-K=2 partials (256 WGs) + fused reduce+rmsnorm
  if (!flat) conv(3);
  gemm256<2><<<dim3(D_ / 256, BT_ / 256, 2), 512, 131072, stream>>>(
      ob, w16[3], oparts, nullptr, BT_, D_, D_, D_, D_, D_);
  addredrms_kernel<<<BT_, 256, 0, stream>>>(oparts, x, g2, x1, hb);

  // gate = h @ Wg ; then hu = silu(gate) * (h @ Wu) via fused epilogue (512 WGs each)
  if (!flat) conv(4);
  gemm256<0><<<dim3(FF_ / 256, BT_ / 256, 1), 512, 131072, stream>>>(
      hb, w16[4], gate, nullptr, BT_, FF_, D_, D_, D_, FF_);
  if (!flat) conv(5);
  gemm256<3><<<dim3(FF_ / 256, BT_ / 256, 1), 512, 131072, stream>>>(
      hb, w16[5], gate, (const float*)gate, BT_, FF_, D_, D_, D_, FF_);

  // Wd split-K=2: partials = hu @ Wd (per half-K), then out = p0 + p1 + x1
  if (!flat) conv(6);
  gemm256<2><<<dim3(D_ / 256, BT_ / 256, 2), 512, 131072, stream>>>(
      gate, w16[6], dparts, nullptr, BT_, D_, FF_, FF_, FF_, D_);
  addred_kernel<<<(BT_ * D_ / 4) / 256, 256, 0, stream>>>(dparts, x1, out);
}

// Round 18
// 1007.114 us; speedup vs baseline: 1.0620x; 1.0620x over previous
//
#include <hip/hip_runtime.h>
#include <cstdint>

#define D_  2048
#define H_  16
#define HD_ 128
#define FF_ 8192
#define T_  2048
#define B_  2
#define BT_ (B_*T_)
#define NP_ (B_*H_)        // 32 (b,h) pairs
#define QKVLD_ (3*D_)      // fused qkv row stride (6144)

typedef __attribute__((ext_vector_type(8))) _Float16 half8;
typedef __attribute__((ext_vector_type(4))) float   floatx4;

// async global->LDS, 16B per lane; LDS dest = wave-uniform base + lane*16
__device__ __forceinline__ void gl_lds16(const void* g, void* l) {
  __builtin_amdgcn_global_load_lds(
      (const __attribute__((address_space(1))) void*)(uintptr_t)g,
      (__attribute__((address_space(3))) void*)(uintptr_t)l,
      16, 0, 0);
}

// ---------------- weight convert + transpose: W[K][N] f32 -> Wt[N][K] f16 ----
// v2: 128k x 32n tiles; float4 global loads and uint2 packed stores giving
// 256B-contiguous output rows. (Kept from R17; fattn regression was separate.)
__global__ void wconv_kernel(const float* __restrict__ W, _Float16* __restrict__ Wt,
                             int K, int N) {
  __shared__ float tile[128][33];
  int n0 = blockIdx.x * 32, k0 = blockIdx.y * 128;
  int tid = threadIdx.x;            // 256
  int lr = tid >> 3;                // 0..31 (row within pass)
  int lc = (tid & 7) * 4;           // 0..28 (f32 col)
#pragma unroll
  for (int p = 0; p < 4; ++p) {
    int r = p * 32 + lr;
    float4 v = *(const float4*)(W + (size_t)(k0 + r) * N + n0 + lc);
    tile[r][lc] = v.x; tile[r][lc + 1] = v.y;
    tile[r][lc + 2] = v.z; tile[r][lc + 3] = v.w;
  }
  __syncthreads();
  int nr = tid >> 5;                // 0..7 (n-row within pass)
  int kc = (tid & 31) * 4;          // 0..124 (k col, step 4)
#pragma unroll
  for (int p = 0; p < 4; ++p) {
    int n = p * 8 + nr;
    _Float16 h4[4] __attribute__((aligned(8)));
    h4[0] = (_Float16)tile[kc][n];
    h4[1] = (_Float16)tile[kc + 1][n];
    h4[2] = (_Float16)tile[kc + 2][n];
    h4[3] = (_Float16)tile[kc + 3][n];
    *(uint2*)(Wt + (size_t)(n0 + n) * K + k0 + kc) = *(const uint2*)h4;
  }
}

// ---------------- rmsnorm: fp32 row -> fp16 row --------------------------------
__global__ void rmsnorm_kernel(const float* __restrict__ x, const float* __restrict__ g,
                               _Float16* __restrict__ out) {
  int row = blockIdx.x, tid = threadIdx.x;
  const float4* xr = (const float4*)(x + (size_t)row * D_);
  float4 v1 = xr[tid], v2 = xr[tid + 256];
  float ss = v1.x*v1.x + v1.y*v1.y + v1.z*v1.z + v1.w*v1.w
           + v2.x*v2.x + v2.y*v2.y + v2.z*v2.z + v2.w*v2.w;
  __shared__ float red[256];
  red[tid] = ss; __syncthreads();
  for (int s = 128; s > 0; s >>= 1) { if (tid < s) red[tid] += red[tid + s]; __syncthreads(); }
  float rs = rsqrtf(red[0] * (1.0f / D_) + 1e-6f);
  float4 ga = ((const float4*)g)[tid], gb = ((const float4*)g)[tid + 256];
  _Float16* orow = out + (size_t)row * D_;
  _Float16 t[4] __attribute__((aligned(8)));
  t[0] = (_Float16)(v1.x * rs * ga.x);
  t[1] = (_Float16)(v1.y * rs * ga.y);
  t[2] = (_Float16)(v1.z * rs * ga.z);
  t[3] = (_Float16)(v1.w * rs * ga.w);
  *(uint2*)(orow + tid * 4) = *(const uint2*)t;
  t[0] = (_Float16)(v2.x * rs * gb.x);
  t[1] = (_Float16)(v2.y * rs * gb.y);
  t[2] = (_Float16)(v2.z * rs * gb.z);
  t[3] = (_Float16)(v2.w * rs * gb.w);
  *(uint2*)(orow + (tid + 256) * 4) = *(const uint2*)t;
}

// ---------------- fused split-K reduce + rmsnorm (Wo path) ----------------------
// x1 = p0 + p1 + res; hb = rmsnorm(x1, g)   (one block per row)
__global__ void addredrms_kernel(const float* __restrict__ parts,
                                 const float* __restrict__ res,
                                 const float* __restrict__ g,
                                 float* __restrict__ x1, _Float16* __restrict__ hb) {
  int row = blockIdx.x, tid = threadIdx.x;
  const size_t MN = (size_t)BT_ * D_;
  size_t base = (size_t)row * D_;
  float4 a1 = *(const float4*)(parts + base + tid * 4);
  float4 b1 = *(const float4*)(parts + MN + base + tid * 4);
  float4 r1 = *(const float4*)(res + base + tid * 4);
  float4 a2 = *(const float4*)(parts + base + (tid + 256) * 4);
  float4 b2 = *(const float4*)(parts + MN + base + (tid + 256) * 4);
  float4 r2 = *(const float4*)(res + base + (tid + 256) * 4);
  float4 v1, v2;
  v1.x = a1.x + b1.x + r1.x; v1.y = a1.y + b1.y + r1.y;
  v1.z = a1.z + b1.z + r1.z; v1.w = a1.w + b1.w + r1.w;
  v2.x = a2.x + b2.x + r2.x; v2.y = a2.y + b2.y + r2.y;
  v2.z = a2.z + b2.z + r2.z; v2.w = a2.w + b2.w + r2.w;
  *(float4*)(x1 + base + tid * 4) = v1;
  *(float4*)(x1 + base + (tid + 256) * 4) = v2;
  float ss = v1.x*v1.x + v1.y*v1.y + v1.z*v1.z + v1.w*v1.w
           + v2.x*v2.x + v2.y*v2.y + v2.z*v2.z + v2.w*v2.w;
  __shared__ float red[256];
  red[tid] = ss; __syncthreads();
  for (int s = 128; s > 0; s >>= 1) { if (tid < s) red[tid] += red[tid + s]; __syncthreads(); }
  float rs = rsqrtf(red[0] * (1.0f / D_) + 1e-6f);
  float4 ga = ((const float4*)g)[tid], gb = ((const float4*)g)[tid + 256];
  _Float16* orow = hb + base;
  _Float16 t[4] __attribute__((aligned(8)));
  t[0] = (_Float16)(v1.x * rs * ga.x);
  t[1] = (_Float16)(v1.y * rs * ga.y);
  t[2] = (_Float16)(v1.z * rs * ga.z);
  t[3] = (_Float16)(v1.w * rs * ga.w);
  *(uint2*)(orow + tid * 4) = *(const uint2*)t;
  t[0] = (_Float16)(v2.x * rs * gb.x);
  t[1] = (_Float16)(v2.y * rs * gb.y);
  t[2] = (_Float16)(v2.z * rs * gb.z);
  t[3] = (_Float16)(v2.w * rs * gb.w);
  *(uint2*)(orow + (tid + 256) * 4) = *(const uint2*)t;
}

// ================================================================================
// 8-phase GEMM (m201 schedule), C = A @ Bt^T. 256x256 tile, BK=64, 8 waves
// (2Mx4N), wave tile 128x64. LDS: [slot0: A 32K | B 32K][slot1] = 128 KiB dbuf.
// K-loop unrolled 2 tiles/iter (literal slots); ds_reads via 8 precomputed
// per-lane base VGPRs + literal imms; stage addrs = 2 advancing pointers.
// vmcnt(4) once per K-tile; never 0 mid-loop. R13/R15-measured config.
// OUTMODE: 0 -> C f16 = acc; 1 -> C f32 = acc + Res; 2 -> C f32 partial at bz;
//          3 -> C f16 = silu(gate[o]) * acc  (gate = (const _Float16*)Res,
//               fused SwiGLU epilogue; may write over gate in place).
template<int OUTMODE>
__global__ __launch_bounds__(512, 2) void gemm256(
    const _Float16* __restrict__ A, const _Float16* __restrict__ Bt,
    void* __restrict__ Cv, const float* __restrict__ Res,
    int M, int N, int K, int lda, int ldb, int ldc)
{
  extern __shared__ _Float16 smem[];   // [2][A:16384 | B:16384] elems

  // XCD-bijective remap
  const int gx = gridDim.x, gy = gridDim.y, gz = gridDim.z;
  int pid = (blockIdx.z * gy + blockIdx.y) * gx + blockIdx.x;
  const int qch = (gx * gy * gz) >> 3;
  int lid = (pid & 7) * qch + (pid >> 3);
  const int bx = lid % gx; lid /= gx;
  const int by = lid % gy; const int bz = lid / gy;

  const int tid  = threadIdx.x;
  const int lane = tid & 63;
  const int w    = tid >> 6;          // 0..7
  const int wm   = w >> 2;            // 0..1
  const int wn   = w & 3;             // 0..3
  const int l15  = lane & 15, q4 = lane >> 4;
  const int m0   = by * 256;
  const int n0   = bx * 256;
  const int KP   = K / gz;
  const int koff = bz * KP;
  const int NT   = KP >> 6;           // K-tiles of 64 (even)

  const int srow8  = lane >> 3;
  const int schunk = (((lane & 7) ^ (srow8 & 7)) << 3);
  const _Float16* AgP = A  + (size_t)(m0 + w * 8 + srow8) * lda + schunk + koff;
  const _Float16* BgP = Bt + (size_t)(n0 + w * 8 + srow8) * ldb + schunk + koff;
  const int ldsW = w * 512;

  const int c0 = ((q4 ^ (l15 & 7)) << 3);
  const int c1 = c0 ^ 32;
  const int arow_e = (wm * 128 + l15) * 64;
  const int brow_e = (wn * 64 + l15) * 64;
  const _Float16* aB[2][2];   // [slot][kk] — literal-indexed only
  const _Float16* bB[2][2];
  aB[0][0] = smem + arow_e + c0;          aB[0][1] = smem + arow_e + c1;
  aB[1][0] = aB[0][0] + 32768;            aB[1][1] = aB[0][1] + 32768;
  bB[0][0] = smem + 16384 + brow_e + c0;  bB[0][1] = smem + 16384 + brow_e + c1;
  bB[1][0] = bB[0][0] + 32768;            bB[1][1] = bB[0][1] + 32768;

  floatx4 acc[8][4];
#pragma unroll
  for (int i = 0; i < 8; ++i)
#pragma unroll
    for (int j = 0; j < 4; ++j)
#pragma unroll
      for (int r = 0; r < 4; ++r) acc[i][j][r] = 0.0f;

  half8 bf[2][4];
  half8 af0[4], af1[4];

#define STA(S, h, s, KO)                                                     \
  gl_lds16(AgP + (size_t)((h) * 128 + (s) * 64) * lda + (KO),                \
           smem + (S) * 32768 + (h) * 8192 + (s) * 4096 + ldsW)
#define STB(S, h, s, KO)                                                     \
  gl_lds16(BgP + (size_t)((h) * 128 + (s) * 64) * ldb + (KO),                \
           smem + (S) * 32768 + 16384 + (h) * 8192 + (s) * 4096 + ldsW)

#define SB0   __builtin_amdgcn_sched_barrier(0)
#define BARR  __builtin_amdgcn_s_barrier()
#define LGKM0 asm volatile("s_waitcnt lgkmcnt(0)" ::: "memory")

#define RD_B8(S)                                                             \
  { _Pragma("unroll")                                                        \
    for (int j = 0; j < 4; ++j) {                                            \
      bf[0][j] = *(const half8*)(bB[S][0] + j * 1024);                       \
      bf[1][j] = *(const half8*)(bB[S][1] + j * 1024);                       \
    } }
#define RD_A4(S, q, af)                                                      \
  { _Pragma("unroll")                                                        \
    for (int i2 = 0; i2 < 2; ++i2) {                                         \
      af[i2*2+0] = *(const half8*)(aB[S][0] + ((q)*2+i2) * 1024);            \
      af[i2*2+1] = *(const half8*)(aB[S][1] + ((q)*2+i2) * 1024);            \
    } }
#define MFMA_Q(q, af)                                                        \
  { _Pragma("unroll")                                                        \
    for (int kk = 0; kk < 2; ++kk)                                           \
      _Pragma("unroll")                                                      \
      for (int i2 = 0; i2 < 2; ++i2)                                         \
        _Pragma("unroll")                                                    \
        for (int j = 0; j < 4; ++j)                                          \
          acc[(q)*2+i2][j] = __builtin_amdgcn_mfma_f32_16x16x32_f16(         \
              af[i2*2+kk], bf[kk][j], acc[(q)*2+i2][j], 0, 0, 0);            \
  }

#define TILE(S, t, KOA, KOB)                                                 \
  {                                                                          \
    const bool s1 = (t) + 1 < NT, s2 = (t) + 2 < NT;                         \
    /* Ph1: all B + A-quad0 */                                               \
    RD_B8(S); RD_A4(S, 0, af0);                                              \
    if (s1) { STA((S) ^ 1, 0, 0, KOA); STA((S) ^ 1, 0, 1, KOA); }            \
    asm volatile("s_waitcnt lgkmcnt(8)" ::: "memory");                       \
    SB0; BARR; LGKM0; SB0;                                                   \
    __builtin_amdgcn_s_setprio(1); MFMA_Q(0, af0); __builtin_amdgcn_s_setprio(0); \
    SB0; BARR;                                                               \
    /* Ph2: A-quad1 */                                                       \
    RD_A4(S, 1, af1);                                                        \
    if (s1) { STA((S) ^ 1, 1, 0, KOA); STA((S) ^ 1, 1, 1, KOA); }            \
    SB0; BARR; LGKM0; SB0;                                                   \
    __builtin_amdgcn_s_setprio(1); MFMA_Q(1, af1); __builtin_amdgcn_s_setprio(0); \
    SB0; BARR;                                                               \
    /* Ph3: A-quad2 */                                                       \
    RD_A4(S, 2, af0);                                                        \
    if (s2) { STB(S, 0, 0, KOB); STB(S, 0, 1, KOB); }                        \
    SB0; BARR; LGKM0; SB0;                                                   \
    __builtin_amdgcn_s_setprio(1); MFMA_Q(2, af0); __builtin_amdgcn_s_setprio(0); \
    SB0; BARR;                                                               \
    /* Ph4: A-quad3 */                                                       \
    RD_A4(S, 3, af1);                                                        \
    if (s2) { STB(S, 1, 0, KOB); STB(S, 1, 1, KOB); }                        \
    SB0; BARR; LGKM0; SB0;                                                   \
    __builtin_amdgcn_s_setprio(1); MFMA_Q(3, af1); __builtin_amdgcn_s_setprio(0); \
    SB0;                                                                     \
    if (s2)      asm volatile("s_waitcnt vmcnt(4)" ::: "memory");            \
    else if (s1) asm volatile("s_waitcnt vmcnt(0)" ::: "memory");            \
    BARR;                                                                    \
  }

  STA(0, 0, 0, 0); STA(0, 0, 1, 0); STA(0, 1, 0, 0); STA(0, 1, 1, 0);
  STB(0, 0, 0, 0); STB(0, 0, 1, 0); STB(0, 1, 0, 0); STB(0, 1, 1, 0);
  if (NT > 1) {
    STB(1, 0, 0, 64); STB(1, 0, 1, 64); STB(1, 1, 0, 64); STB(1, 1, 1, 64);
    asm volatile("s_waitcnt vmcnt(4)" ::: "memory");
  } else {
    asm volatile("s_waitcnt vmcnt(0)" ::: "memory");
  }
  BARR;

  for (int t = 0; t < NT; t += 2) {
    TILE(0, t,     64, 128);
    TILE(1, t + 1, 128, 192);
    AgP += 128; BgP += 128;
  }

#undef STA
#undef STB
#undef SB0
#undef BARR
#undef LGKM0
#undef RD_B8
#undef RD_A4
#undef MFMA_Q
#undef TILE

  const int crow0 = m0 + wm * 128 + q4 * 4;
  const int ccol0 = n0 + wn * 64 + l15;
#pragma unroll
  for (int i = 0; i < 8; ++i)
#pragma unroll
    for (int j = 0; j < 4; ++j)
#pragma unroll
      for (int r = 0; r < 4; ++r) {
        size_t o = (size_t)(crow0 + i * 16 + r) * ldc + (ccol0 + j * 16);
        if constexpr (OUTMODE == 0)      ((_Float16*)Cv)[o] = (_Float16)acc[i][j][r];
        else if constexpr (OUTMODE == 1) ((float*)Cv)[o] = acc[i][j][r] + Res[o];
        else if constexpr (OUTMODE == 3) {
          float gv = (float)((const _Float16*)Res)[o];
          float si = gv / (1.0f + __expf(-gv));
          ((_Float16*)Cv)[o] = (_Float16)(si * acc[i][j][r]);
        }
        else ((float*)Cv)[(size_t)bz * M * ldc + o] = acc[i][j][r];
      }
}

// ---------------- split-K reduce: out = p0 + p1 + res (all f32) -----------------
__global__ void addred_kernel(const float* __restrict__ parts, const float* __restrict__ res,
                              float* __restrict__ out) {
  size_t i = ((size_t)blockIdx.x * 256 + threadIdx.x) * 4;
  const size_t MN = (size_t)BT_ * D_;
  float4 a = *(const float4*)(parts + i);
  float4 b = *(const float4*)(parts + MN + i);
  float4 r = *(const float4*)(res + i);
  float4 o;
  o.x = a.x + b.x + r.x; o.y = a.y + b.y + r.y;
  o.z = a.z + b.z + r.z; o.w = a.w + b.w + r.w;
  *(float4*)(out + i) = o;
}

// ================================================================================
// K pack: post-rope K -> fragment-contiguous kp[pair][t/16][d/32][lane][8].
__global__ void kpack_kernel(const _Float16* __restrict__ qkv, _Float16* __restrict__ kp) {
  __shared__ _Float16 tile[32][40];    // [t][d], padded
  int t0 = blockIdx.x * 32, d0 = blockIdx.y * 32, bh = blockIdx.z;
  int b = bh >> 4, h = bh & 15;
  int tx = threadIdx.x, ty = threadIdx.y;   // 32 x 8
  const _Float16* kb = qkv + (size_t)b * T_ * QKVLD_ + D_ + (size_t)h * HD_;
#pragma unroll
  for (int r = 0; r < 32; r += 8)
    tile[ty + r][tx] = kb[(size_t)(t0 + ty + r) * QKVLD_ + d0 + tx];
  __syncthreads();
  int tid = ty * 32 + tx;
  if (tid < 128) {
    int tt = tid & 31;            // t within tile
    int c  = tid >> 5;            // d chunk of 8 (0..3)
    int t = t0 + tt, d = d0 + c * 8;
    _Float16 v8[8] __attribute__((aligned(16)));
#pragma unroll
    for (int e = 0; e < 8; ++e) v8[e] = tile[tt][c * 8 + e];
    size_t frag = ((size_t)bh * (T_ / 16) + (t >> 4)) * 4 + (d >> 5);
    int lane = (t & 15) + (((d >> 3) & 3) << 4);
    *(uint4*)(kp + frag * 512 + lane * 8) = *(const uint4*)v8;
  }
}

// ---------------- V pack: qkv V -> V^T fragments vp[pair][t/128][ks][jd][lane][8]
__global__ void vpack_kernel(const _Float16* __restrict__ qkv, _Float16* __restrict__ vp) {
  __shared__ _Float16 tile[32][40];    // [t][d], padded
  int t0 = blockIdx.x * 32, d0 = blockIdx.y * 32, bh = blockIdx.z;
  int b = bh >> 4, h = bh & 15;
  int tx = threadIdx.x, ty = threadIdx.y;   // 32 x 8
  const _Float16* vb = qkv + (size_t)b * T_ * QKVLD_ + 2 * D_ + (size_t)h * HD_;
#pragma unroll
  for (int r = 0; r < 32; r += 8)
    tile[ty + r][tx] = vb[(size_t)(t0 + ty + r) * QKVLD_ + d0 + tx];
  __syncthreads();
  int tid = ty * 32 + tx;
  if (tid < 128) {
    int dd = tid & 31;            // d within tile
    int tg = tid >> 5;            // t chunk of 8 (0..3)
    int d = d0 + dd, t = t0 + tg * 8;
    _Float16 v8[8] __attribute__((aligned(16)));
#pragma unroll
    for (int e = 0; e < 8; ++e) v8[e] = tile[tg * 8 + e][dd];
    size_t frag = (((size_t)bh * 16 + (t >> 7)) * 4 + ((t >> 5) & 3)) * 8 + (d >> 4);
    int lane = (d & 15) + (((t >> 3) & 3) << 4);
    *(uint4*)(vp + frag * 512 + lane * 8) = *(const uint4*)v8;
  }
}

// ================================================================================
// Fused flash attention (causal). R16-verified config (byte-for-byte softmax):
// one 128-row q-block per WG, 4 waves, grid (32 pairs, 16) = 512 WGs, (256,2)
// -> ~128 VGPR, no spills. K/V from PACKED fragment layouts (base + lane*16,
// fully coalesced). 8-wide double-buffered K/V batches; V batch0 issued
// before softmax. setprio(1) around both MFMA clusters (T5). UNCONDITIONAL
// rescale (R17's defer branch caused ~220 MB spill traffic; reverted).
// Online softmax f32 via shfl_xor; P via wave-private LDS rows (no barriers).
__global__ __launch_bounds__(256, 2) void fattn_kernel(
    const _Float16* __restrict__ qkv, const _Float16* __restrict__ kp,
    const _Float16* __restrict__ vp, _Float16* __restrict__ ob)
{
  __shared__ _Float16 Pl[128 * 136];   // row stride 136 f16 (pad vs bank conflicts)
  const int pr = blockIdx.x;           // pair 0..31
  const int yq = blockIdx.y;           // 0..15
  const int qb = (yq < 8) ? yq : 23 - yq;   // CU-pair work balance
  const int b = pr >> 4, h = pr & 15;
  const int lane = threadIdx.x & 63, w = threadIdx.x >> 6;
  const int l15 = lane & 15, q4 = lane >> 4;
  const float scale = 0.08838834764831845f;   // 1/sqrt(128)

  const _Float16* qg = qkv + (size_t)b * T_ * QKVLD_ + (size_t)h * HD_;
  _Float16* og = ob + (size_t)b * T_ * D_ + (size_t)h * HD_;
  const _Float16* kpp = kp + (size_t)pr * 128 * 4 * 512 + lane * 8;
  const _Float16* vpp = vp + (size_t)pr * 16 * 32 * 512 + lane * 8;

  const int qrow0 = qb * 128 + w * 32;

  // Q fragments: lane holds Q[row=l15(+16i)][k=kf*32+q4*8 .. +8]
  half8 qf[2][4];
#pragma unroll
  for (int i = 0; i < 2; ++i)
#pragma unroll
    for (int kf = 0; kf < 4; ++kf)
      qf[i][kf] = *(const half8*)(qg + (size_t)(qrow0 + i * 16 + l15) * QKVLD_
                                     + kf * 32 + q4 * 8);

  floatx4 Oa[2][8];
  float m[8], l[8];
#pragma unroll
  for (int i = 0; i < 2; ++i)
#pragma unroll
    for (int j = 0; j < 8; ++j)
#pragma unroll
      for (int r = 0; r < 4; ++r) Oa[i][j][r] = 0.f;
#pragma unroll
  for (int z = 0; z < 8; ++z) { m[z] = -1e30f; l[z] = 0.f; }

  for (int kt = 0; kt <= qb; ++kt) {
    // K fragment (j, kf) at kT + (j*4 + kf)*512
    const _Float16* kT = kpp + (size_t)kt * 8 * 4 * 512;
    half8 k0[8], k1[8];
#pragma unroll
    for (int j = 0; j < 8; ++j)
      k0[j] = *(const half8*)(kT + j * 2048);
    floatx4 s[2][8];
#pragma unroll
    for (int i = 0; i < 2; ++i)
#pragma unroll
      for (int j = 0; j < 8; ++j)
#pragma unroll
        for (int r = 0; r < 4; ++r) s[i][j][r] = 0.f;
#pragma unroll
    for (int kf = 0; kf < 4; ++kf) {
      if (kf < 3) {
#pragma unroll
        for (int j = 0; j < 8; ++j) {
          half8 nx = *(const half8*)(kT + j * 2048 + (kf + 1) * 512);
          if (kf & 1) k0[j] = nx; else k1[j] = nx;
        }
      }
      __builtin_amdgcn_s_setprio(1);
#pragma unroll
      for (int j = 0; j < 8; ++j) {
        half8 cur = (kf & 1) ? k1[j] : k0[j];
        s[0][j] = __builtin_amdgcn_mfma_f32_16x16x32_f16(qf[0][kf], cur, s[0][j], 0, 0, 0);
        s[1][j] = __builtin_amdgcn_mfma_f32_16x16x32_f16(qf[1][kf], cur, s[1][j], 0, 0, 0);
      }
      __builtin_amdgcn_s_setprio(0);
    }
    // scale (f32, matches reference order)
#pragma unroll
    for (int i = 0; i < 2; ++i)
#pragma unroll
      for (int j = 0; j < 8; ++j)
#pragma unroll
        for (int r = 0; r < 4; ++r) s[i][j][r] *= scale;
    // causal mask (diagonal tile only)
    if (kt == qb) {
#pragma unroll
      for (int i = 0; i < 2; ++i)
#pragma unroll
        for (int j = 0; j < 8; ++j)
#pragma unroll
          for (int r = 0; r < 4; ++r)
            if (j * 16 + l15 > w * 32 + i * 16 + q4 * 4 + r) s[i][j][r] = -1e30f;
    }
    // ---- V ks=0 batch (fragment (ks, jd) at vT + (ks*8 + jd)*512) ----
    const _Float16* vT = vpp + (size_t)kt * 32 * 512;
    half8 v0[8], v1[8];
#pragma unroll
    for (int jd = 0; jd < 8; ++jd)
      v0[jd] = *(const half8*)(vT + jd * 512);
    // ---- online softmax (per lane: 8 rows = 2i x 4r) ----
#pragma unroll
    for (int i = 0; i < 2; ++i)
#pragma unroll
      for (int r = 0; r < 4; ++r) {
        const int z = i * 4 + r;
        float pm = s[i][0][r];
#pragma unroll
        for (int j = 1; j < 8; ++j) pm = fmaxf(pm, s[i][j][r]);
        pm = fmaxf(pm, __shfl_xor(pm, 1));
        pm = fmaxf(pm, __shfl_xor(pm, 2));
        pm = fmaxf(pm, __shfl_xor(pm, 4));
        pm = fmaxf(pm, __shfl_xor(pm, 8));
        float mn = fmaxf(m[z], pm);
        float sc = __expf(m[z] - mn);
        m[z] = mn;
        float ls = 0.f;
#pragma unroll
        for (int j = 0; j < 8; ++j) {
          float e = __expf(s[i][j][r] - mn);
          s[i][j][r] = e;
          ls += e;
        }
        ls += __shfl_xor(ls, 1);
        ls += __shfl_xor(ls, 2);
        ls += __shfl_xor(ls, 4);
        ls += __shfl_xor(ls, 8);
        l[z] = l[z] * sc + ls;
#pragma unroll
        for (int jd = 0; jd < 8; ++jd) Oa[i][jd][r] *= sc;
      }
    // ---- P -> LDS (wave-private rows; no barrier needed) ----
#pragma unroll
    for (int i = 0; i < 2; ++i)
#pragma unroll
      for (int r = 0; r < 4; ++r) {
        _Float16* prow = &Pl[(size_t)(w * 32 + i * 16 + q4 * 4 + r) * 136 + l15];
#pragma unroll
        for (int j = 0; j < 8; ++j) prow[j * 16] = (_Float16)s[i][j][r];
      }
    // ---- O += P @ V, V double-buffered over ks ----
#pragma unroll
    for (int ks = 0; ks < 4; ++ks) {
      if (ks < 3) {
#pragma unroll
        for (int jd = 0; jd < 8; ++jd) {
          half8 nx = *(const half8*)(vT + ((ks + 1) * 8 + jd) * 512);
          if (ks & 1) v0[jd] = nx; else v1[jd] = nx;
        }
      }
      half8 pf0 = *(const half8*)&Pl[(size_t)(w * 32 + l15) * 136 + ks * 32 + q4 * 8];
      half8 pf1 = *(const half8*)&Pl[(size_t)(w * 32 + 16 + l15) * 136 + ks * 32 + q4 * 8];
      __builtin_amdgcn_s_setprio(1);
#pragma unroll
      for (int jd = 0; jd < 8; ++jd) {
        half8 vf = (ks & 1) ? v1[jd] : v0[jd];
        Oa[0][jd] = __builtin_amdgcn_mfma_f32_16x16x32_f16(pf0, vf, Oa[0][jd], 0, 0, 0);
        Oa[1][jd] = __builtin_amdgcn_mfma_f32_16x16x32_f16(pf1, vf, Oa[1][jd], 0, 0, 0);
      }
      __builtin_amdgcn_s_setprio(0);
    }
  }
  // ---- epilogue: O / l -> ob ----
#pragma unroll
  for (int i = 0; i < 2; ++i)
#pragma unroll
    for (int r = 0; r < 4; ++r) {
      float inv = 1.0f / l[i * 4 + r];
      _Float16* orow = og + (size_t)(qrow0 + i * 16 + q4 * 4 + r) * D_;
#pragma unroll
      for (int jd = 0; jd < 8; ++jd)
        orow[jd * 16 + l15] = (_Float16)(Oa[i][jd][r] * inv);
    }
}

// ---------------- RoPE on fused qkv (q at col 0, k at col D_) -------------------
__global__ void rope_kernel(_Float16* __restrict__ qkv, const void* __restrict__ pos) {
  int gid = blockIdx.x * 256 + threadIdx.x;   // BT_*H_*64 threads
  int d = gid & 63;
  int h = (gid >> 6) & 15;
  int bt = gid >> 10;
  const int* pi = (const int*)pos;
  long long pv = (pi[1] == 0 && pi[2] == 1) ? ((const long long*)pos)[bt]
                                            : (long long)pi[bt];
  float inv = exp2f((float)d * -0.2076205059304601f);  // 10000^(-d/64)
  float ang = (float)pv * inv;
  float s, c;
  sincosf(ang, &s, &c);
  size_t base = (size_t)bt * QKVLD_ + (size_t)h * HD_ + d;
  _Float16* q = qkv;
  _Float16* k = qkv + D_;
  float x1v = (float)q[base], x2v = (float)q[base + 64];
  q[base]      = (_Float16)(x1v * c - x2v * s);
  q[base + 64] = (_Float16)(x2v * c + x1v * s);
  x1v = (float)k[base]; x2v = (float)k[base + 64];
  k[base]      = (_Float16)(x1v * c - x2v * s);
  k[base + 64] = (_Float16)(x2v * c + x1v * s);
}

// ================================================================================
extern "C" void kernel_launch(void* const* d_in, const int* in_sizes, int n_in,
                              void* d_out, int out_size, void* d_ws, size_t ws_size,
                              hipStream_t stream) {
  (void)in_sizes; (void)n_in; (void)out_size;
  const float* x   = (const float*)d_in[0];
  const void*  pos = d_in[1];
  const float* W[7] = { (const float*)d_in[2], (const float*)d_in[3],
                        (const float*)d_in[4], (const float*)d_in[5],
                        (const float*)d_in[6], (const float*)d_in[7],
                        (const float*)d_in[8] };              // q k v o g u d
  const float* g1  = (const float*)d_in[9];
  const float* g2  = (const float*)d_in[10];
  float* out = (float*)d_out;

  const int wk[7] = { D_, D_, D_, D_, D_, D_, FF_ };
  const int wn[7] = { D_, D_, D_, D_, FF_, FF_, D_ };

  char* p = (char*)d_ws;
  auto carve = [&](size_t bytes) { char* r = p; p += (bytes + 255) & ~(size_t)255; return r; };

  _Float16* scratch = (_Float16*)carve((size_t)64 * 1024 * 1024);  // Wo parts / gate
  const size_t FLAT_NEED = (size_t)336 * 1024 * 1024;
  bool flat = ws_size >= FLAT_NEED;
  _Float16* w16[7];
  if (flat) {
    // q,k,v carved contiguously -> fused QKV weight matrix [6144][2048]
    for (int i = 0; i < 7; i++) w16[i] = (_Float16*)carve((size_t)wk[i] * wn[i] * 2);
  } else {
    _Float16* wslot = (_Float16*)carve((size_t)D_ * FF_ * 2);      // 32 MB slot
    w16[0] = wslot;
    w16[1] = wslot + (size_t)D_ * D_;
    w16[2] = wslot + (size_t)2 * D_ * D_;
    w16[3] = w16[4] = w16[5] = w16[6] = wslot;
  }
  _Float16* qkv = (_Float16*)carve((size_t)BT_ * QKVLD_ * 2);  // 48 MB
  _Float16* ob  = (_Float16*)carve((size_t)BT_ * D_ * 2);      // 16 MB (contig after qkv)
  _Float16* xn  = (_Float16*)carve((size_t)BT_ * D_ * 2);      // 16 MB; later: kp, hb
  _Float16* vt  = (_Float16*)carve((size_t)BT_ * D_ * 2);      // 16 MB (vp)
  float*    x1  = (float*)   carve((size_t)BT_ * D_ * 4);      // 32 MB
  _Float16* gate = scratch;      // 64 MB region; becomes hu in place (OUTMODE 3)
  _Float16* hb   = xn;
  _Float16* kpb  = xn;           // K packed (16 MB); xn dead after qkv GEMM, reborn as hb later
  _Float16* vpb  = vt;           // V packed (16 MB)
  float* oparts = (float*)scratch; // Wo split-K partials (2 x 32 MB)
  float* dparts = (float*)qkv;     // Wd split-K partials (2 x 32 MB); qkv dead by then

  dim3 b328(32, 8);
  auto conv = [&](int i) {
    wconv_kernel<<<dim3(wn[i] / 32, wk[i] / 128), 256, 0, stream>>>(W[i], w16[i], wk[i], wn[i]);
  };
  if (flat) for (int i = 0; i < 7; i++) conv(i);

  // xn = rmsnorm(x, g1)
  rmsnorm_kernel<<<BT_, 256, 0, stream>>>(x, g1, xn);

  // fused qkv projection: [BT][6144] = xn @ [Wq;Wk;Wv]^T   (384 WGs)
  if (!flat) { conv(0); conv(1); conv(2); }
  gemm256<0><<<dim3(QKVLD_ / 256, BT_ / 256, 1), 512, 131072, stream>>>(
      xn, w16[0], qkv, nullptr, BT_, QKVLD_, D_, D_, D_, QKVLD_);

  // rope(q, k) in fused layout
  rope_kernel<<<(BT_ * H_ * 64) / 256, 256, 0, stream>>>(qkv, pos);

  // pack K (post-rope) and V into MFMA-fragment-contiguous layouts
  kpack_kernel<<<dim3(T_ / 32, HD_ / 32, NP_), b328, 0, stream>>>(qkv, kpb);
  vpack_kernel<<<dim3(T_ / 32, HD_ / 32, NP_), b328, 0, stream>>>(qkv, vpb);

  // fused flash attention: ob = softmax(QK^T/sqrt(d), causal) @ V  (512 WGs)
  fattn_kernel<<<dim3(NP_, 16), 256, 0, stream>>>(qkv, kpb, vpb, ob);

  // x1 = x + o @ Wo : split-K=2 partials (256 WGs) + fused reduce+rmsnorm
  if (!flat) conv(3);
  gemm256<2><<<dim3(D_ / 256, BT_ / 256, 2), 512, 131072, stream>>>(
      ob, w16[3], oparts, nullptr, BT_, D_, D_, D_, D_, D_);
  addredrms_kernel<<<BT_, 256, 0, stream>>>(oparts, x, g2, x1, hb);

  // gate = h @ Wg ; then hu = silu(gate) * (h @ Wu) via fused epilogue (512 WGs each)
  if (!flat) conv(4);
  gemm256<0><<<dim3(FF_ / 256, BT_ / 256, 1), 512, 131072, stream>>>(
      hb, w16[4], gate, nullptr, BT_, FF_, D_, D_, D_, FF_);
  if (!flat) conv(5);
  gemm256<3><<<dim3(FF_ / 256, BT_ / 256, 1), 512, 131072, stream>>>(
      hb, w16[5], gate, (const float*)gate, BT_, FF_, D_, D_, D_, FF_);

  // Wd split-K=2: partials = hu @ Wd (per half-K), then out = p0 + p1 + x1
  if (!flat) conv(6);
  gemm256<2><<<dim3(D_ / 256, BT_ / 256, 2), 512, 131072, stream>>>(
      gate, w16[6], dparts, nullptr, BT_, D_, FF_, FF_, FF_, D_);
  addred_kernel<<<(BT_ * D_ / 4) / 256, 256, 0, stream>>>(dparts, x1, out);
}

// Round 19
// 1006.033 us; speedup vs baseline: 1.0632x; 1.0011x over previous
//
#include <hip/hip_runtime.h>
#include <cstdint>

#define D_  2048
#define H_  16
#define HD_ 128
#define FF_ 8192
#define T_  2048
#define B_  2
#define BT_ (B_*T_)
#define NP_ (B_*H_)        // 32 (b,h) pairs
#define QKVLD_ (3*D_)      // fused qkv row stride (6144)

typedef __attribute__((ext_vector_type(8))) _Float16 half8;
typedef __attribute__((ext_vector_type(4))) float   floatx4;

// async global->LDS, 16B per lane; LDS dest = wave-uniform base + lane*16
__device__ __forceinline__ void gl_lds16(const void* g, void* l) {
  __builtin_amdgcn_global_load_lds(
      (const __attribute__((address_space(1))) void*)(uintptr_t)g,
      (__attribute__((address_space(3))) void*)(uintptr_t)l,
      16, 0, 0);
}

// ---------------- weight convert + transpose: W[K][N] f32 -> Wt[N][K] f16 ----
// v2: 128k x 32n tiles; float4 global loads and uint2 packed stores giving
// 256B-contiguous output rows.
__global__ void wconv_kernel(const float* __restrict__ W, _Float16* __restrict__ Wt,
                             int K, int N) {
  __shared__ float tile[128][33];
  int n0 = blockIdx.x * 32, k0 = blockIdx.y * 128;
  int tid = threadIdx.x;            // 256
  int lr = tid >> 3;                // 0..31 (row within pass)
  int lc = (tid & 7) * 4;           // 0..28 (f32 col)
#pragma unroll
  for (int p = 0; p < 4; ++p) {
    int r = p * 32 + lr;
    float4 v = *(const float4*)(W + (size_t)(k0 + r) * N + n0 + lc);
    tile[r][lc] = v.x; tile[r][lc + 1] = v.y;
    tile[r][lc + 2] = v.z; tile[r][lc + 3] = v.w;
  }
  __syncthreads();
  int nr = tid >> 5;                // 0..7 (n-row within pass)
  int kc = (tid & 31) * 4;          // 0..124 (k col, step 4)
#pragma unroll
  for (int p = 0; p < 4; ++p) {
    int n = p * 8 + nr;
    _Float16 h4[4] __attribute__((aligned(8)));
    h4[0] = (_Float16)tile[kc][n];
    h4[1] = (_Float16)tile[kc + 1][n];
    h4[2] = (_Float16)tile[kc + 2][n];
    h4[3] = (_Float16)tile[kc + 3][n];
    *(uint2*)(Wt + (size_t)(n0 + n) * K + k0 + kc) = *(const uint2*)h4;
  }
}

// ---------------- rmsnorm: fp32 row -> fp16 row --------------------------------
__global__ void rmsnorm_kernel(const float* __restrict__ x, const float* __restrict__ g,
                               _Float16* __restrict__ out) {
  int row = blockIdx.x, tid = threadIdx.x;
  const float4* xr = (const float4*)(x + (size_t)row * D_);
  float4 v1 = xr[tid], v2 = xr[tid + 256];
  float ss = v1.x*v1.x + v1.y*v1.y + v1.z*v1.z + v1.w*v1.w
           + v2.x*v2.x + v2.y*v2.y + v2.z*v2.z + v2.w*v2.w;
  __shared__ float red[256];
  red[tid] = ss; __syncthreads();
  for (int s = 128; s > 0; s >>= 1) { if (tid < s) red[tid] += red[tid + s]; __syncthreads(); }
  float rs = rsqrtf(red[0] * (1.0f / D_) + 1e-6f);
  float4 ga = ((const float4*)g)[tid], gb = ((const float4*)g)[tid + 256];
  _Float16* orow = out + (size_t)row * D_;
  _Float16 t[4] __attribute__((aligned(8)));
  t[0] = (_Float16)(v1.x * rs * ga.x);
  t[1] = (_Float16)(v1.y * rs * ga.y);
  t[2] = (_Float16)(v1.z * rs * ga.z);
  t[3] = (_Float16)(v1.w * rs * ga.w);
  *(uint2*)(orow + tid * 4) = *(const uint2*)t;
  t[0] = (_Float16)(v2.x * rs * gb.x);
  t[1] = (_Float16)(v2.y * rs * gb.y);
  t[2] = (_Float16)(v2.z * rs * gb.z);
  t[3] = (_Float16)(v2.w * rs * gb.w);
  *(uint2*)(orow + (tid + 256) * 4) = *(const uint2*)t;
}

// ---------------- fused split-K reduce + rmsnorm (Wo path) ----------------------
// x1 = p0 + p1 + res; hb = rmsnorm(x1, g)   (one block per row)
__global__ void addredrms_kernel(const float* __restrict__ parts,
                                 const float* __restrict__ res,
                                 const float* __restrict__ g,
                                 float* __restrict__ x1, _Float16* __restrict__ hb) {
  int row = blockIdx.x, tid = threadIdx.x;
  const size_t MN = (size_t)BT_ * D_;
  size_t base = (size_t)row * D_;
  float4 a1 = *(const float4*)(parts + base + tid * 4);
  float4 b1 = *(const float4*)(parts + MN + base + tid * 4);
  float4 r1 = *(const float4*)(res + base + tid * 4);
  float4 a2 = *(const float4*)(parts + base + (tid + 256) * 4);
  float4 b2 = *(const float4*)(parts + MN + base + (tid + 256) * 4);
  float4 r2 = *(const float4*)(res + base + (tid + 256) * 4);
  float4 v1, v2;
  v1.x = a1.x + b1.x + r1.x; v1.y = a1.y + b1.y + r1.y;
  v1.z = a1.z + b1.z + r1.z; v1.w = a1.w + b1.w + r1.w;
  v2.x = a2.x + b2.x + r2.x; v2.y = a2.y + b2.y + r2.y;
  v2.z = a2.z + b2.z + r2.z; v2.w = a2.w + b2.w + r2.w;
  *(float4*)(x1 + base + tid * 4) = v1;
  *(float4*)(x1 + base + (tid + 256) * 4) = v2;
  float ss = v1.x*v1.x + v1.y*v1.y + v1.z*v1.z + v1.w*v1.w
           + v2.x*v2.x + v2.y*v2.y + v2.z*v2.z + v2.w*v2.w;
  __shared__ float red[256];
  red[tid] = ss; __syncthreads();
  for (int s = 128; s > 0; s >>= 1) { if (tid < s) red[tid] += red[tid + s]; __syncthreads(); }
  float rs = rsqrtf(red[0] * (1.0f / D_) + 1e-6f);
  float4 ga = ((const float4*)g)[tid], gb = ((const float4*)g)[tid + 256];
  _Float16* orow = hb + base;
  _Float16 t[4] __attribute__((aligned(8)));
  t[0] = (_Float16)(v1.x * rs * ga.x);
  t[1] = (_Float16)(v1.y * rs * ga.y);
  t[2] = (_Float16)(v1.z * rs * ga.z);
  t[3] = (_Float16)(v1.w * rs * ga.w);
  *(uint2*)(orow + tid * 4) = *(const uint2*)t;
  t[0] = (_Float16)(v2.x * rs * gb.x);
  t[1] = (_Float16)(v2.y * rs * gb.y);
  t[2] = (_Float16)(v2.z * rs * gb.z);
  t[3] = (_Float16)(v2.w * rs * gb.w);
  *(uint2*)(orow + (tid + 256) * 4) = *(const uint2*)t;
}

// ================================================================================
// 8-phase GEMM (m201 schedule), C = A @ Bt^T. 256x256 tile, BK=64, 8 waves
// (2Mx4N), wave tile 128x64. LDS: [slot0: A 32K | B 32K][slot1] = 128 KiB dbuf.
// K-loop unrolled 2 tiles/iter (literal slots); ds_reads via 8 precomputed
// per-lane base VGPRs + literal imms; stage addrs = 2 advancing pointers.
// vmcnt(4) once per K-tile; never 0 mid-loop.
// XCD remap decode is Y-FASTEST (this round's single change): each XCD owns a
// narrow bx band x all by -> B (weight) panels L2-resident instead of every
// XCD streaming the whole B matrix (x-fastest measured 270 MB FETCH vs ~160
// ideal at gate/up shape). Bijective either way; math identical.
// OUTMODE: 0 -> C f16 = acc; 1 -> C f32 = acc + Res; 2 -> C f32 partial at bz;
//          3 -> C f16 = silu(gate[o]) * acc  (gate = (const _Float16*)Res).
template<int OUTMODE>
__global__ __launch_bounds__(512, 2) void gemm256(
    const _Float16* __restrict__ A, const _Float16* __restrict__ Bt,
    void* __restrict__ Cv, const float* __restrict__ Res,
    int M, int N, int K, int lda, int ldb, int ldc)
{
  extern __shared__ _Float16 smem[];   // [2][A:16384 | B:16384] elems

  // XCD-bijective remap (y-fastest decode)
  const int gx = gridDim.x, gy = gridDim.y, gz = gridDim.z;
  int pid = (blockIdx.z * gy + blockIdx.y) * gx + blockIdx.x;
  const int qch = (gx * gy * gz) >> 3;
  int lid = (pid & 7) * qch + (pid >> 3);
  const int by = lid % gy; lid /= gy;
  const int bx = lid % gx; const int bz = lid / gx;

  const int tid  = threadIdx.x;
  const int lane = tid & 63;
  const int w    = tid >> 6;          // 0..7
  const int wm   = w >> 2;            // 0..1
  const int wn   = w & 3;             // 0..3
  const int l15  = lane & 15, q4 = lane >> 4;
  const int m0   = by * 256;
  const int n0   = bx * 256;
  const int KP   = K / gz;
  const int koff = bz * KP;
  const int NT   = KP >> 6;           // K-tiles of 64 (even)

  const int srow8  = lane >> 3;
  const int schunk = (((lane & 7) ^ (srow8 & 7)) << 3);
  const _Float16* AgP = A  + (size_t)(m0 + w * 8 + srow8) * lda + schunk + koff;
  const _Float16* BgP = Bt + (size_t)(n0 + w * 8 + srow8) * ldb + schunk + koff;
  const int ldsW = w * 512;

  const int c0 = ((q4 ^ (l15 & 7)) << 3);
  const int c1 = c0 ^ 32;
  const int arow_e = (wm * 128 + l15) * 64;
  const int brow_e = (wn * 64 + l15) * 64;
  const _Float16* aB[2][2];   // [slot][kk] — literal-indexed only
  const _Float16* bB[2][2];
  aB[0][0] = smem + arow_e + c0;          aB[0][1] = smem + arow_e + c1;
  aB[1][0] = aB[0][0] + 32768;            aB[1][1] = aB[0][1] + 32768;
  bB[0][0] = smem + 16384 + brow_e + c0;  bB[0][1] = smem + 16384 + brow_e + c1;
  bB[1][0] = bB[0][0] + 32768;            bB[1][1] = bB[0][1] + 32768;

  floatx4 acc[8][4];
#pragma unroll
  for (int i = 0; i < 8; ++i)
#pragma unroll
    for (int j = 0; j < 4; ++j)
#pragma unroll
      for (int r = 0; r < 4; ++r) acc[i][j][r] = 0.0f;

  half8 bf[2][4];
  half8 af0[4], af1[4];

#define STA(S, h, s, KO)                                                     \
  gl_lds16(AgP + (size_t)((h) * 128 + (s) * 64) * lda + (KO),                \
           smem + (S) * 32768 + (h) * 8192 + (s) * 4096 + ldsW)
#define STB(S, h, s, KO)                                                     \
  gl_lds16(BgP + (size_t)((h) * 128 + (s) * 64) * ldb + (KO),                \
           smem + (S) * 32768 + 16384 + (h) * 8192 + (s) * 4096 + ldsW)

#define SB0   __builtin_amdgcn_sched_barrier(0)
#define BARR  __builtin_amdgcn_s_barrier()
#define LGKM0 asm volatile("s_waitcnt lgkmcnt(0)" ::: "memory")

#define RD_B8(S)                                                             \
  { _Pragma("unroll")                                                        \
    for (int j = 0; j < 4; ++j) {                                            \
      bf[0][j] = *(const half8*)(bB[S][0] + j * 1024);                       \
      bf[1][j] = *(const half8*)(bB[S][1] + j * 1024);                       \
    } }
#define RD_A4(S, q, af)                                                      \
  { _Pragma("unroll")                                                        \
    for (int i2 = 0; i2 < 2; ++i2) {                                         \
      af[i2*2+0] = *(const half8*)(aB[S][0] + ((q)*2+i2) * 1024);            \
      af[i2*2+1] = *(const half8*)(aB[S][1] + ((q)*2+i2) * 1024);            \
    } }
#define MFMA_Q(q, af)                                                        \
  { _Pragma("unroll")                                                        \
    for (int kk = 0; kk < 2; ++kk)                                           \
      _Pragma("unroll")                                                      \
      for (int i2 = 0; i2 < 2; ++i2)                                         \
        _Pragma("unroll")                                                    \
        for (int j = 0; j < 4; ++j)                                          \
          acc[(q)*2+i2][j] = __builtin_amdgcn_mfma_f32_16x16x32_f16(         \
              af[i2*2+kk], bf[kk][j], acc[(q)*2+i2][j], 0, 0, 0);            \
  }

#define TILE(S, t, KOA, KOB)                                                 \
  {                                                                          \
    const bool s1 = (t) + 1 < NT, s2 = (t) + 2 < NT;                         \
    /* Ph1: all B + A-quad0 */                                               \
    RD_B8(S); RD_A4(S, 0, af0);                                              \
    if (s1) { STA((S) ^ 1, 0, 0, KOA); STA((S) ^ 1, 0, 1, KOA); }            \
    asm volatile("s_waitcnt lgkmcnt(8)" ::: "memory");                       \
    SB0; BARR; LGKM0; SB0;                                                   \
    __builtin_amdgcn_s_setprio(1); MFMA_Q(0, af0); __builtin_amdgcn_s_setprio(0); \
    SB0; BARR;                                                               \
    /* Ph2: A-quad1 */                                                       \
    RD_A4(S, 1, af1);                                                        \
    if (s1) { STA((S) ^ 1, 1, 0, KOA); STA((S) ^ 1, 1, 1, KOA); }            \
    SB0; BARR; LGKM0; SB0;                                                   \
    __builtin_amdgcn_s_setprio(1); MFMA_Q(1, af1); __builtin_amdgcn_s_setprio(0); \
    SB0; BARR;                                                               \
    /* Ph3: A-quad2 */                                                       \
    RD_A4(S, 2, af0);                                                        \
    if (s2) { STB(S, 0, 0, KOB); STB(S, 0, 1, KOB); }                        \
    SB0; BARR; LGKM0; SB0;                                                   \
    __builtin_amdgcn_s_setprio(1); MFMA_Q(2, af0); __builtin_amdgcn_s_setprio(0); \
    SB0; BARR;                                                               \
    /* Ph4: A-quad3 */                                                       \
    RD_A4(S, 3, af1);                                                        \
    if (s2) { STB(S, 1, 0, KOB); STB(S, 1, 1, KOB); }                        \
    SB0; BARR; LGKM0; SB0;                                                   \
    __builtin_amdgcn_s_setprio(1); MFMA_Q(3, af1); __builtin_amdgcn_s_setprio(0); \
    SB0;                                                                     \
    if (s2)      asm volatile("s_waitcnt vmcnt(4)" ::: "memory");            \
    else if (s1) asm volatile("s_waitcnt vmcnt(0)" ::: "memory");            \
    BARR;                                                                    \
  }

  STA(0, 0, 0, 0); STA(0, 0, 1, 0); STA(0, 1, 0, 0); STA(0, 1, 1, 0);
  STB(0, 0, 0, 0); STB(0, 0, 1, 0); STB(0, 1, 0, 0); STB(0, 1, 1, 0);
  if (NT > 1) {
    STB(1, 0, 0, 64); STB(1, 0, 1, 64); STB(1, 1, 0, 64); STB(1, 1, 1, 64);
    asm volatile("s_waitcnt vmcnt(4)" ::: "memory");
  } else {
    asm volatile("s_waitcnt vmcnt(0)" ::: "memory");
  }
  BARR;

  for (int t = 0; t < NT; t += 2) {
    TILE(0, t,     64, 128);
    TILE(1, t + 1, 128, 192);
    AgP += 128; BgP += 128;
  }

#undef STA
#undef STB
#undef SB0
#undef BARR
#undef LGKM0
#undef RD_B8
#undef RD_A4
#undef MFMA_Q
#undef TILE

  const int crow0 = m0 + wm * 128 + q4 * 4;
  const int ccol0 = n0 + wn * 64 + l15;
#pragma unroll
  for (int i = 0; i < 8; ++i)
#pragma unroll
    for (int j = 0; j < 4; ++j)
#pragma unroll
      for (int r = 0; r < 4; ++r) {
        size_t o = (size_t)(crow0 + i * 16 + r) * ldc + (ccol0 + j * 16);
        if constexpr (OUTMODE == 0)      ((_Float16*)Cv)[o] = (_Float16)acc[i][j][r];
        else if constexpr (OUTMODE == 1) ((float*)Cv)[o] = acc[i][j][r] + Res[o];
        else if constexpr (OUTMODE == 3) {
          float gv = (float)((const _Float16*)Res)[o];
          float si = gv / (1.0f + __expf(-gv));
          ((_Float16*)Cv)[o] = (_Float16)(si * acc[i][j][r]);
        }
        else ((float*)Cv)[(size_t)bz * M * ldc + o] = acc[i][j][r];
      }
}

// ---------------- split-K reduce: out = p0 + p1 + res (all f32) -----------------
__global__ void addred_kernel(const float* __restrict__ parts, const float* __restrict__ res,
                              float* __restrict__ out) {
  size_t i = ((size_t)blockIdx.x * 256 + threadIdx.x) * 4;
  const size_t MN = (size_t)BT_ * D_;
  float4 a = *(const float4*)(parts + i);
  float4 b = *(const float4*)(parts + MN + i);
  float4 r = *(const float4*)(res + i);
  float4 o;
  o.x = a.x + b.x + r.x; o.y = a.y + b.y + r.y;
  o.z = a.z + b.z + r.z; o.w = a.w + b.w + r.w;
  *(float4*)(out + i) = o;
}

// ================================================================================
// K pack: post-rope K -> fragment-contiguous kp[pair][t/16][d/32][lane][8].
__global__ void kpack_kernel(const _Float16* __restrict__ qkv, _Float16* __restrict__ kp) {
  __shared__ _Float16 tile[32][40];    // [t][d], padded
  int t0 = blockIdx.x * 32, d0 = blockIdx.y * 32, bh = blockIdx.z;
  int b = bh >> 4, h = bh & 15;
  int tx = threadIdx.x, ty = threadIdx.y;   // 32 x 8
  const _Float16* kb = qkv + (size_t)b * T_ * QKVLD_ + D_ + (size_t)h * HD_;
#pragma unroll
  for (int r = 0; r < 32; r += 8)
    tile[ty + r][tx] = kb[(size_t)(t0 + ty + r) * QKVLD_ + d0 + tx];
  __syncthreads();
  int tid = ty * 32 + tx;
  if (tid < 128) {
    int tt = tid & 31;            // t within tile
    int c  = tid >> 5;            // d chunk of 8 (0..3)
    int t = t0 + tt, d = d0 + c * 8;
    _Float16 v8[8] __attribute__((aligned(16)));
#pragma unroll
    for (int e = 0; e < 8; ++e) v8[e] = tile[tt][c * 8 + e];
    size_t frag = ((size_t)bh * (T_ / 16) + (t >> 4)) * 4 + (d >> 5);
    int lane = (t & 15) + (((d >> 3) & 3) << 4);
    *(uint4*)(kp + frag * 512 + lane * 8) = *(const uint4*)v8;
  }
}

// ---------------- V pack: qkv V -> V^T fragments vp[pair][t/128][ks][jd][lane][8]
__global__ void vpack_kernel(const _Float16* __restrict__ qkv, _Float16* __restrict__ vp) {
  __shared__ _Float16 tile[32][40];    // [t][d], padded
  int t0 = blockIdx.x * 32, d0 = blockIdx.y * 32, bh = blockIdx.z;
  int b = bh >> 4, h = bh & 15;
  int tx = threadIdx.x, ty = threadIdx.y;   // 32 x 8
  const _Float16* vb = qkv + (size_t)b * T_ * QKVLD_ + 2 * D_ + (size_t)h * HD_;
#pragma unroll
  for (int r = 0; r < 32; r += 8)
    tile[ty + r][tx] = vb[(size_t)(t0 + ty + r) * QKVLD_ + d0 + tx];
  __syncthreads();
  int tid = ty * 32 + tx;
  if (tid < 128) {
    int dd = tid & 31;            // d within tile
    int tg = tid >> 5;            // t chunk of 8 (0..3)
    int d = d0 + dd, t = t0 + tg * 8;
    _Float16 v8[8] __attribute__((aligned(16)));
#pragma unroll
    for (int e = 0; e < 8; ++e) v8[e] = tile[tg * 8 + e][dd];
    size_t frag = (((size_t)bh * 16 + (t >> 7)) * 4 + ((t >> 5) & 3)) * 8 + (d >> 4);
    int lane = (d & 15) + (((t >> 3) & 3) << 4);
    *(uint4*)(vp + frag * 512 + lane * 8) = *(const uint4*)v8;
  }
}

// ================================================================================
// Fused flash attention (causal). R16/R18-verified config (byte-for-byte):
// one 128-row q-block per WG, 4 waves, grid (32 pairs, 16) = 512 WGs, (256,2)
// -> ~128 VGPR, no spills. K/V from PACKED fragment layouts (base + lane*16,
// fully coalesced). 8-wide double-buffered K/V batches; V batch0 issued
// before softmax. setprio(1) around both MFMA clusters (T5). Unconditional
// rescale. Online softmax f32 via shfl_xor; P via wave-private LDS rows.
__global__ __launch_bounds__(256, 2) void fattn_kernel(
    const _Float16* __restrict__ qkv, const _Float16* __restrict__ kp,
    const _Float16* __restrict__ vp, _Float16* __restrict__ ob)
{
  __shared__ _Float16 Pl[128 * 136];   // row stride 136 f16 (pad vs bank conflicts)
  const int pr = blockIdx.x;           // pair 0..31
  const int yq = blockIdx.y;           // 0..15
  const int qb = (yq < 8) ? yq : 23 - yq;   // CU-pair work balance
  const int b = pr >> 4, h = pr & 15;
  const int lane = threadIdx.x & 63, w = threadIdx.x >> 6;
  const int l15 = lane & 15, q4 = lane >> 4;
  const float scale = 0.08838834764831845f;   // 1/sqrt(128)

  const _Float16* qg = qkv + (size_t)b * T_ * QKVLD_ + (size_t)h * HD_;
  _Float16* og = ob + (size_t)b * T_ * D_ + (size_t)h * HD_;
  const _Float16* kpp = kp + (size_t)pr * 128 * 4 * 512 + lane * 8;
  const _Float16* vpp = vp + (size_t)pr * 16 * 32 * 512 + lane * 8;

  const int qrow0 = qb * 128 + w * 32;

  // Q fragments: lane holds Q[row=l15(+16i)][k=kf*32+q4*8 .. +8]
  half8 qf[2][4];
#pragma unroll
  for (int i = 0; i < 2; ++i)
#pragma unroll
    for (int kf = 0; kf < 4; ++kf)
      qf[i][kf] = *(const half8*)(qg + (size_t)(qrow0 + i * 16 + l15) * QKVLD_
                                     + kf * 32 + q4 * 8);

  floatx4 Oa[2][8];
  float m[8], l[8];
#pragma unroll
  for (int i = 0; i < 2; ++i)
#pragma unroll
    for (int j = 0; j < 8; ++j)
#pragma unroll
      for (int r = 0; r < 4; ++r) Oa[i][j][r] = 0.f;
#pragma unroll
  for (int z = 0; z < 8; ++z) { m[z] = -1e30f; l[z] = 0.f; }

  for (int kt = 0; kt <= qb; ++kt) {
    // K fragment (j, kf) at kT + (j*4 + kf)*512
    const _Float16* kT = kpp + (size_t)kt * 8 * 4 * 512;
    half8 k0[8], k1[8];
#pragma unroll
    for (int j = 0; j < 8; ++j)
      k0[j] = *(const half8*)(kT + j * 2048);
    floatx4 s[2][8];
#pragma unroll
    for (int i = 0; i < 2; ++i)
#pragma unroll
      for (int j = 0; j < 8; ++j)
#pragma unroll
        for (int r = 0; r < 4; ++r) s[i][j][r] = 0.f;
#pragma unroll
    for (int kf = 0; kf < 4; ++kf) {
      if (kf < 3) {
#pragma unroll
        for (int j = 0; j < 8; ++j) {
          half8 nx = *(const half8*)(kT + j * 2048 + (kf + 1) * 512);
          if (kf & 1) k0[j] = nx; else k1[j] = nx;
        }
      }
      __builtin_amdgcn_s_setprio(1);
#pragma unroll
      for (int j = 0; j < 8; ++j) {
        half8 cur = (kf & 1) ? k1[j] : k0[j];
        s[0][j] = __builtin_amdgcn_mfma_f32_16x16x32_f16(qf[0][kf], cur, s[0][j], 0, 0, 0);
        s[1][j] = __builtin_amdgcn_mfma_f32_16x16x32_f16(qf[1][kf], cur, s[1][j], 0, 0, 0);
      }
      __builtin_amdgcn_s_setprio(0);
    }
    // scale (f32, matches reference order)
#pragma unroll
    for (int i = 0; i < 2; ++i)
#pragma unroll
      for (int j = 0; j < 8; ++j)
#pragma unroll
        for (int r = 0; r < 4; ++r) s[i][j][r] *= scale;
    // causal mask (diagonal tile only)
    if (kt == qb) {
#pragma unroll
      for (int i = 0; i < 2; ++i)
#pragma unroll
        for (int j = 0; j < 8; ++j)
#pragma unroll
          for (int r = 0; r < 4; ++r)
            if (j * 16 + l15 > w * 32 + i * 16 + q4 * 4 + r) s[i][j][r] = -1e30f;
    }
    // ---- V ks=0 batch (fragment (ks, jd) at vT + (ks*8 + jd)*512) ----
    const _Float16* vT = vpp + (size_t)kt * 32 * 512;
    half8 v0[8], v1[8];
#pragma unroll
    for (int jd = 0; jd < 8; ++jd)
      v0[jd] = *(const half8*)(vT + jd * 512);
    // ---- online softmax (per lane: 8 rows = 2i x 4r) ----
#pragma unroll
    for (int i = 0; i < 2; ++i)
#pragma unroll
      for (int r = 0; r < 4; ++r) {
        const int z = i * 4 + r;
        float pm = s[i][0][r];
#pragma unroll
        for (int j = 1; j < 8; ++j) pm = fmaxf(pm, s[i][j][r]);
        pm = fmaxf(pm, __shfl_xor(pm, 1));
        pm = fmaxf(pm, __shfl_xor(pm, 2));
        pm = fmaxf(pm, __shfl_xor(pm, 4));
        pm = fmaxf(pm, __shfl_xor(pm, 8));
        float mn = fmaxf(m[z], pm);
        float sc = __expf(m[z] - mn);
        m[z] = mn;
        float ls = 0.f;
#pragma unroll
        for (int j = 0; j < 8; ++j) {
          float e = __expf(s[i][j][r] - mn);
          s[i][j][r] = e;
          ls += e;
        }
        ls += __shfl_xor(ls, 1);
        ls += __shfl_xor(ls, 2);
        ls += __shfl_xor(ls, 4);
        ls += __shfl_xor(ls, 8);
        l[z] = l[z] * sc + ls;
#pragma unroll
        for (int jd = 0; jd < 8; ++jd) Oa[i][jd][r] *= sc;
      }
    // ---- P -> LDS (wave-private rows; no barrier needed) ----
#pragma unroll
    for (int i = 0; i < 2; ++i)
#pragma unroll
      for (int r = 0; r < 4; ++r) {
        _Float16* prow = &Pl[(size_t)(w * 32 + i * 16 + q4 * 4 + r) * 136 + l15];
#pragma unroll
        for (int j = 0; j < 8; ++j) prow[j * 16] = (_Float16)s[i][j][r];
      }
    // ---- O += P @ V, V double-buffered over ks ----
#pragma unroll
    for (int ks = 0; ks < 4; ++ks) {
      if (ks < 3) {
#pragma unroll
        for (int jd = 0; jd < 8; ++jd) {
          half8 nx = *(const half8*)(vT + ((ks + 1) * 8 + jd) * 512);
          if (ks & 1) v0[jd] = nx; else v1[jd] = nx;
        }
      }
      half8 pf0 = *(const half8*)&Pl[(size_t)(w * 32 + l15) * 136 + ks * 32 + q4 * 8];
      half8 pf1 = *(const half8*)&Pl[(size_t)(w * 32 + 16 + l15) * 136 + ks * 32 + q4 * 8];
      __builtin_amdgcn_s_setprio(1);
#pragma unroll
      for (int jd = 0; jd < 8; ++jd) {
        half8 vf = (ks & 1) ? v1[jd] : v0[jd];
        Oa[0][jd] = __builtin_amdgcn_mfma_f32_16x16x32_f16(pf0, vf, Oa[0][jd], 0, 0, 0);
        Oa[1][jd] = __builtin_amdgcn_mfma_f32_16x16x32_f16(pf1, vf, Oa[1][jd], 0, 0, 0);
      }
      __builtin_amdgcn_s_setprio(0);
    }
  }
  // ---- epilogue: O / l -> ob ----
#pragma unroll
  for (int i = 0; i < 2; ++i)
#pragma unroll
    for (int r = 0; r < 4; ++r) {
      float inv = 1.0f / l[i * 4 + r];
      _Float16* orow = og + (size_t)(qrow0 + i * 16 + q4 * 4 + r) * D_;
#pragma unroll
      for (int jd = 0; jd < 8; ++jd)
        orow[jd * 16 + l15] = (_Float16)(Oa[i][jd][r] * inv);
    }
}

// ---------------- RoPE on fused qkv (q at col 0, k at col D_) -------------------
__global__ void rope_kernel(_Float16* __restrict__ qkv, const void* __restrict__ pos) {
  int gid = blockIdx.x * 256 + threadIdx.x;   // BT_*H_*64 threads
  int d = gid & 63;
  int h = (gid >> 6) & 15;
  int bt = gid >> 10;
  const int* pi = (const int*)pos;
  long long pv = (pi[1] == 0 && pi[2] == 1) ? ((const long long*)pos)[bt]
                                            : (long long)pi[bt];
  float inv = exp2f((float)d * -0.2076205059304601f);  // 10000^(-d/64)
  float ang = (float)pv * inv;
  float s, c;
  sincosf(ang, &s, &c);
  size_t base = (size_t)bt * QKVLD_ + (size_t)h * HD_ + d;
  _Float16* q = qkv;
  _Float16* k = qkv + D_;
  float x1v = (float)q[base], x2v = (float)q[base + 64];
  q[base]      = (_Float16)(x1v * c - x2v * s);
  q[base + 64] = (_Float16)(x2v * c + x1v * s);
  x1v = (float)k[base]; x2v = (float)k[base + 64];
  k[base]      = (_Float16)(x1v * c - x2v * s);
  k[base + 64] = (_Float16)(x2v * c + x1v * s);
}

// ================================================================================
extern "C" void kernel_launch(void* const* d_in, const int* in_sizes, int n_in,
                              void* d_out, int out_size, void* d_ws, size_t ws_size,
                              hipStream_t stream) {
  (void)in_sizes; (void)n_in; (void)out_size;
  const float* x   = (const float*)d_in[0];
  const void*  pos = d_in[1];
  const float* W[7] = { (const float*)d_in[2], (const float*)d_in[3],
                        (const float*)d_in[4], (const float*)d_in[5],
                        (const float*)d_in[6], (const float*)d_in[7],
                        (const float*)d_in[8] };              // q k v o g u d
  const float* g1  = (const float*)d_in[9];
  const float* g2  = (const float*)d_in[10];
  float* out = (float*)d_out;

  const int wk[7] = { D_, D_, D_, D_, D_, D_, FF_ };
  const int wn[7] = { D_, D_, D_, D_, FF_, FF_, D_ };

  char* p = (char*)d_ws;
  auto carve = [&](size_t bytes) { char* r = p; p += (bytes + 255) & ~(size_t)255; return r; };

  _Float16* scratch = (_Float16*)carve((size_t)64 * 1024 * 1024);  // Wo parts / gate
  const size_t FLAT_NEED = (size_t)336 * 1024 * 1024;
  bool flat = ws_size >= FLAT_NEED;
  _Float16* w16[7];
  if (flat) {
    // q,k,v carved contiguously -> fused QKV weight matrix [6144][2048]
    for (int i = 0; i < 7; i++) w16[i] = (_Float16*)carve((size_t)wk[i] * wn[i] * 2);
  } else {
    _Float16* wslot = (_Float16*)carve((size_t)D_ * FF_ * 2);      // 32 MB slot
    w16[0] = wslot;
    w16[1] = wslot + (size_t)D_ * D_;
    w16[2] = wslot + (size_t)2 * D_ * D_;
    w16[3] = w16[4] = w16[5] = w16[6] = wslot;
  }
  _Float16* qkv = (_Float16*)carve((size_t)BT_ * QKVLD_ * 2);  // 48 MB
  _Float16* ob  = (_Float16*)carve((size_t)BT_ * D_ * 2);      // 16 MB (contig after qkv)
  _Float16* xn  = (_Float16*)carve((size_t)BT_ * D_ * 2);      // 16 MB; later: kp, hb
  _Float16* vt  = (_Float16*)carve((size_t)BT_ * D_ * 2);      // 16 MB (vp)
  float*    x1  = (float*)   carve((size_t)BT_ * D_ * 4);      // 32 MB
  _Float16* gate = scratch;      // 64 MB region; becomes hu in place (OUTMODE 3)
  _Float16* hb   = xn;
  _Float16* kpb  = xn;           // K packed (16 MB); xn dead after qkv GEMM, reborn as hb later
  _Float16* vpb  = vt;           // V packed (16 MB)
  float* oparts = (float*)scratch; // Wo split-K partials (2 x 32 MB)
  float* dparts = (float*)qkv;     // Wd split-K partials (2 x 32 MB); qkv dead by then

  dim3 b328(32, 8);
  auto conv = [&](int i) {
    wconv_kernel<<<dim3(wn[i] / 32, wk[i] / 128), 256, 0, stream>>>(W[i], w16[i], wk[i], wn[i]);
  };
  if (flat) for (int i = 0; i < 7; i++) conv(i);

  // xn = rmsnorm(x, g1)
  rmsnorm_kernel<<<BT_, 256, 0, stream>>>(x, g1, xn);

  // fused qkv projection: [BT][6144] = xn @ [Wq;Wk;Wv]^T   (384 WGs)
  if (!flat) { conv(0); conv(1); conv(2); }
  gemm256<0><<<dim3(QKVLD_ / 256, BT_ / 256, 1), 512, 131072, stream>>>(
      xn, w16[0], qkv, nullptr, BT_, QKVLD_, D_, D_, D_, QKVLD_);

  // rope(q, k) in fused layout
  rope_kernel<<<(BT_ * H_ * 64) / 256, 256, 0, stream>>>(qkv, pos);

  // pack K (post-rope) and V into MFMA-fragment-contiguous layouts
  kpack_kernel<<<dim3(T_ / 32, HD_ / 32, NP_), b328, 0, stream>>>(qkv, kpb);
  vpack_kernel<<<dim3(T_ / 32, HD_ / 32, NP_), b328, 0, stream>>>(qkv, vpb);

  // fused flash attention: ob = softmax(QK^T/sqrt(d), causal) @ V  (512 WGs)
  fattn_kernel<<<dim3(NP_, 16), 256, 0, stream>>>(qkv, kpb, vpb, ob);

  // x1 = x + o @ Wo : split-K=2 partials (256 WGs) + fused reduce+rmsnorm
  if (!flat) conv(3);
  gemm256<2><<<dim3(D_ / 256, BT_ / 256, 2), 512, 131072, stream>>>(
      ob, w16[3], oparts, nullptr, BT_, D_, D_, D_, D_, D_);
  addredrms_kernel<<<BT_, 256, 0, stream>>>(oparts, x, g2, x1, hb);

  // gate = h @ Wg ; then hu = silu(gate) * (h @ Wu) via fused epilogue (512 WGs each)
  if (!flat) conv(4);
  gemm256<0><<<dim3(FF_ / 256, BT_ / 256, 1), 512, 131072, stream>>>(
      hb, w16[4], gate, nullptr, BT_, FF_, D_, D_, D_, FF_);
  if (!flat) conv(5);
  gemm256<3><<<dim3(FF_ / 256, BT_ / 256, 1), 512, 131072, stream>>>(
      hb, w16[5], gate, (const float*)gate, BT_, FF_, D_, D_, D_, FF_);

  // Wd split-K=2: partials = hu @ Wd (per half-K), then out = p0 + p1 + x1
  if (!flat) conv(6);
  gemm256<2><<<dim3(D_ / 256, BT_ / 256, 2), 512, 131072, stream>>>(
      gate, w16[6], dparts, nullptr, BT_, D_, FF_, FF_, FF_, D_);
  addred_kernel<<<(BT_ * D_ / 4) / 256, 256, 0, stream>>>(dparts, x1, out);
}